// Round 1
// baseline (5748.184 us; speedup 1.0000x reference)
//
#include <hip/hip_runtime.h>

#define NHID 256
#define NFEAT 512

// ---------------- GEMM: C[M,N] = (RELU?relu(A):A)[M,K] @ B[K,N] ----------------
// 64x64 tile, BK=16, 256 threads, 4x4 per thread. N multiple of 64, K multiple of 16.
template <bool RELU>
__global__ __launch_bounds__(256) void gemm_tiled(const float* __restrict__ A,
                                                  const float* __restrict__ B,
                                                  float* __restrict__ C,
                                                  int M, int N, int K) {
    __shared__ float As[16][65];  // [k][m], +1 pad
    __shared__ float Bs[16][64];  // [k][n]

    const int block_row = blockIdx.x * 64;
    const int block_col = blockIdx.y * 64;
    const int tid = threadIdx.x;
    const int tx = tid & 15;   // 0..15 -> 4 cols each
    const int ty = tid >> 4;   // 0..15 -> 4 rows each

    float c[4][4] = {};

    for (int k0 = 0; k0 < K; k0 += 16) {
        // A tile: 64 rows x 16 k  (1024 elems, 4 per thread)
#pragma unroll
        for (int i = 0; i < 4; ++i) {
            int idx = tid + i * 256;
            int kk = idx & 15;
            int m = idx >> 4;
            int row = block_row + m;
            float v = 0.f;
            if (row < M) v = A[(long)row * K + k0 + kk];
            if (RELU) v = fmaxf(v, 0.f);
            As[kk][m] = v;
        }
        // B tile: 16 k x 64 n
#pragma unroll
        for (int i = 0; i < 4; ++i) {
            int idx = tid + i * 256;
            int n = idx & 63;
            int kk = idx >> 6;
            Bs[kk][n] = B[(long)(k0 + kk) * N + block_col + n];
        }
        __syncthreads();
#pragma unroll
        for (int kk = 0; kk < 16; ++kk) {
            float a[4], b[4];
#pragma unroll
            for (int i = 0; i < 4; ++i) a[i] = As[kk][ty * 4 + i];
#pragma unroll
            for (int j = 0; j < 4; ++j) b[j] = Bs[kk][tx * 4 + j];
#pragma unroll
            for (int i = 0; i < 4; ++i)
#pragma unroll
                for (int j = 0; j < 4; ++j) c[i][j] += a[i] * b[j];
        }
        __syncthreads();
    }

#pragma unroll
    for (int i = 0; i < 4; ++i) {
        int row = block_row + ty * 4 + i;
        if (row < M) {
            float* cp = C + (long)row * N + block_col + tx * 4;
#pragma unroll
            for (int j = 0; j < 4; ++j) cp[j] = c[i][j];
        }
    }
}

// ---------------- Edge scatter: z[dst] += w * h[src], 256 features ----------------
// One wave (64 lanes) per edge; lane handles 4 consecutive feats (float4 load).
__global__ __launch_bounds__(256) void scatter_conv(const float* __restrict__ h,
                                                    const int* __restrict__ src,
                                                    const int* __restrict__ dst,
                                                    const float* __restrict__ w,
                                                    float* __restrict__ z, int E) {
    const int lane = threadIdx.x & 63;
    const int wid = threadIdx.x >> 6;
    const int nwaves = (gridDim.x * blockDim.x) >> 6;
    for (int e = blockIdx.x * 4 + wid; e < E; e += nwaves) {
        int s = src[e];
        int d = dst[e];
        float ww = w[e];
        float4 v = ((const float4*)(h + (long)s * NHID))[lane];
        float* zp = z + (long)d * NHID + lane * 4;
        atomicAdd(zp + 0, ww * v.x);
        atomicAdd(zp + 1, ww * v.y);
        atomicAdd(zp + 2, ww * v.z);
        atomicAdd(zp + 3, ww * v.w);
    }
}

// ---------------- Decode: out[p] = concat(z[ps], z[pd]) @ Wlin[512,2] ----------------
// One wave per pos-edge. Each lane owns 4 feats of each endpoint; Wlin slice in regs.
__global__ __launch_bounds__(256) void decode_kernel(const float* __restrict__ z,
                                                     const int* __restrict__ ps,
                                                     const int* __restrict__ pd,
                                                     const float* __restrict__ Wlin,
                                                     float* __restrict__ out, int P) {
    const int lane = threadIdx.x & 63;
    const int wid = threadIdx.x >> 6;
    const int nwaves = (gridDim.x * blockDim.x) >> 6;

    // Per-lane Wlin slice: rows lane*4..lane*4+3 (src part) and 256+lane*4.. (dst part)
    float wa[8], wb[8];
#pragma unroll
    for (int i = 0; i < 8; ++i) {
        wa[i] = Wlin[(lane * 4) * 2 + i];
        wb[i] = Wlin[(NHID + lane * 4) * 2 + i];
    }

    for (int p = blockIdx.x * 4 + wid; p < P; p += nwaves) {
        int a = ps[p];
        int b = pd[p];
        float4 va = ((const float4*)(z + (long)a * NHID))[lane];
        float4 vb = ((const float4*)(z + (long)b * NHID))[lane];
        float acc0 = va.x * wa[0] + va.y * wa[2] + va.z * wa[4] + va.w * wa[6]
                   + vb.x * wb[0] + vb.y * wb[2] + vb.z * wb[4] + vb.w * wb[6];
        float acc1 = va.x * wa[1] + va.y * wa[3] + va.z * wa[5] + va.w * wa[7]
                   + vb.x * wb[1] + vb.y * wb[3] + vb.z * wb[5] + vb.w * wb[7];
#pragma unroll
        for (int off = 32; off > 0; off >>= 1) {
            acc0 += __shfl_down(acc0, off);
            acc1 += __shfl_down(acc1, off);
        }
        if (lane == 0) {
            out[(long)p * 2 + 0] = acc0;
            out[(long)p * 2 + 1] = acc1;
        }
    }
}

extern "C" void kernel_launch(void* const* d_in, const int* in_sizes, int n_in,
                              void* d_out, int out_size, void* d_ws, size_t ws_size,
                              hipStream_t stream) {
    (void)n_in; (void)out_size; (void)ws_size;
    const float* x    = (const float*)d_in[0];   // [N, 512]
    const int*   ei   = (const int*)d_in[1];     // [2, E]
    const float* ew   = (const float*)d_in[2];   // [E]
    const int*   pei  = (const int*)d_in[3];     // [2, P]
    const float* W1   = (const float*)d_in[4];   // [512, 256]
    const float* W2   = (const float*)d_in[5];   // [256, 256]
    const float* Wlin = (const float*)d_in[6];   // [512, 2]
    float* out = (float*)d_out;                  // [P, 2]

    const int E = in_sizes[2];
    const int P = in_sizes[3] / 2;
    const int N = in_sizes[0] / NFEAT;

    float* bufA = (float*)d_ws;                // h1 then h2  [N,256]
    float* bufB = bufA + (size_t)N * NHID;     // z1 then z2  [N,256]
    const size_t zbytes = (size_t)N * NHID * sizeof(float);

    dim3 blk(256);
    dim3 gemm_grid((N + 63) / 64, NHID / 64);

    // h1 = x @ W1
    gemm_tiled<false><<<gemm_grid, blk, 0, stream>>>(x, W1, bufA, N, NHID, NFEAT);
    // z1 = scatter(h1)
    hipMemsetAsync(bufB, 0, zbytes, stream);
    scatter_conv<<<2048, blk, 0, stream>>>(bufA, ei, ei + E, ew, bufB, E);
    // h2 = relu(z1) @ W2
    gemm_tiled<true><<<gemm_grid, blk, 0, stream>>>(bufB, W2, bufA, N, NHID, NHID);
    // z2 = scatter(h2)
    hipMemsetAsync(bufB, 0, zbytes, stream);
    scatter_conv<<<2048, blk, 0, stream>>>(bufA, ei, ei + E, ew, bufB, E);
    // out = concat-gather @ Wlin
    decode_kernel<<<(P + 3) / 4, blk, 0, stream>>>(bufB, pei, pei + P, Wlin, out, P);
}

// Round 2
// 832.946 us; speedup vs baseline: 6.9010x; 6.9010x over previous
//
#include <hip/hip_runtime.h>

#define NHID 256
#define NFEAT 512

// ---------------- GEMM: C[M,N] = (RELU?relu(A):A)[M,K] @ B[K,N] ----------------
template <bool RELU>
__global__ __launch_bounds__(256) void gemm_tiled(const float* __restrict__ A,
                                                  const float* __restrict__ B,
                                                  float* __restrict__ C,
                                                  int M, int N, int K) {
    __shared__ float As[16][65];
    __shared__ float Bs[16][64];

    const int block_row = blockIdx.x * 64;
    const int block_col = blockIdx.y * 64;
    const int tid = threadIdx.x;
    const int tx = tid & 15;
    const int ty = tid >> 4;

    float c[4][4] = {};

    for (int k0 = 0; k0 < K; k0 += 16) {
#pragma unroll
        for (int i = 0; i < 4; ++i) {
            int idx = tid + i * 256;
            int kk = idx & 15;
            int m = idx >> 4;
            int row = block_row + m;
            float v = 0.f;
            if (row < M) v = A[(long)row * K + k0 + kk];
            if (RELU) v = fmaxf(v, 0.f);
            As[kk][m] = v;
        }
#pragma unroll
        for (int i = 0; i < 4; ++i) {
            int idx = tid + i * 256;
            int n = idx & 63;
            int kk = idx >> 6;
            Bs[kk][n] = B[(long)(k0 + kk) * N + block_col + n];
        }
        __syncthreads();
#pragma unroll
        for (int kk = 0; kk < 16; ++kk) {
            float a[4], b[4];
#pragma unroll
            for (int i = 0; i < 4; ++i) a[i] = As[kk][ty * 4 + i];
#pragma unroll
            for (int j = 0; j < 4; ++j) b[j] = Bs[kk][tx * 4 + j];
#pragma unroll
            for (int i = 0; i < 4; ++i)
#pragma unroll
                for (int j = 0; j < 4; ++j) c[i][j] += a[i] * b[j];
        }
        __syncthreads();
    }

#pragma unroll
    for (int i = 0; i < 4; ++i) {
        int row = block_row + ty * 4 + i;
        if (row < M) {
            float* cp = C + (long)row * N + block_col + tx * 4;
#pragma unroll
            for (int j = 0; j < 4; ++j) cp[j] = c[i][j];
        }
    }
}

// ---------------- CSR build: histogram, scan, ticket-scatter ----------------
__global__ __launch_bounds__(256) void hist_kernel(const int* __restrict__ dst,
                                                   int* __restrict__ counts, int E) {
    for (int e = blockIdx.x * blockDim.x + threadIdx.x; e < E; e += gridDim.x * blockDim.x)
        atomicAdd(&counts[dst[e]], 1);
}

// Single block, 1024 threads. counts may alias cursor (read-before-write per index).
__global__ __launch_bounds__(1024) void scan_kernel(const int* __restrict__ counts,
                                                    int* __restrict__ offsets,
                                                    int* __restrict__ cursor, int n) {
    __shared__ int sums[1024];
    const int tid = threadIdx.x;
    const int chunk = (n + 1023) / 1024;
    const int begin = min(tid * chunk, n);
    const int end = min(begin + chunk, n);
    int s = 0;
    for (int i = begin; i < end; ++i) s += counts[i];
    sums[tid] = s;
    __syncthreads();
    for (int off = 1; off < 1024; off <<= 1) {
        int v = (tid >= off) ? sums[tid - off] : 0;
        __syncthreads();
        sums[tid] += v;
        __syncthreads();
    }
    int prefix = (tid == 0) ? 0 : sums[tid - 1];
    for (int i = begin; i < end; ++i) {
        int c = counts[i];     // read BEFORE cursor write (alias-safe)
        offsets[i] = prefix;
        cursor[i] = prefix;
        prefix += c;
    }
    if (tid == 1023) offsets[n] = prefix;
}

__global__ __launch_bounds__(256) void sort_edges(const int* __restrict__ src,
                                                  const int* __restrict__ dst,
                                                  const float* __restrict__ w,
                                                  int* __restrict__ cursor,
                                                  int* __restrict__ ssrc,
                                                  float* __restrict__ sw, int E) {
    for (int e = blockIdx.x * blockDim.x + threadIdx.x; e < E; e += gridDim.x * blockDim.x) {
        int d = dst[e];
        int pos = atomicAdd(&cursor[d], 1);
        ssrc[pos] = src[e];
        sw[pos] = w[e];
    }
}

// ---------------- Gather conv: z[n] = sum over in-edges w * h[src] ----------------
// One wave per node; lane owns 4 consecutive feats (float4).
__global__ __launch_bounds__(256) void gather_conv(const float* __restrict__ h,
                                                   const int* __restrict__ offsets,
                                                   const int* __restrict__ ssrc,
                                                   const float* __restrict__ sw,
                                                   float* __restrict__ z, int N) {
    const int lane = threadIdx.x & 63;
    const int wid = threadIdx.x >> 6;
    const int node = blockIdx.x * 4 + wid;
    if (node >= N) return;
    const int s0 = offsets[node];
    const int s1 = offsets[node + 1];
    float4 acc = {0.f, 0.f, 0.f, 0.f};
    for (int i = s0; i < s1; ++i) {
        int s = ssrc[i];
        float ww = sw[i];
        float4 v = ((const float4*)(h + (long)s * NHID))[lane];
        acc.x += ww * v.x;
        acc.y += ww * v.y;
        acc.z += ww * v.z;
        acc.w += ww * v.w;
    }
    ((float4*)(z + (long)node * NHID))[lane] = acc;
}

// ---------------- Fallback atomic scatter (if ws too small for CSR) ----------------
__global__ __launch_bounds__(256) void scatter_conv(const float* __restrict__ h,
                                                    const int* __restrict__ src,
                                                    const int* __restrict__ dst,
                                                    const float* __restrict__ w,
                                                    float* __restrict__ z, int E) {
    const int lane = threadIdx.x & 63;
    const int wid = threadIdx.x >> 6;
    const int nwaves = (gridDim.x * blockDim.x) >> 6;
    for (int e = blockIdx.x * 4 + wid; e < E; e += nwaves) {
        int s = src[e];
        int d = dst[e];
        float ww = w[e];
        float4 v = ((const float4*)(h + (long)s * NHID))[lane];
        float* zp = z + (long)d * NHID + lane * 4;
        atomicAdd(zp + 0, ww * v.x);
        atomicAdd(zp + 1, ww * v.y);
        atomicAdd(zp + 2, ww * v.z);
        atomicAdd(zp + 3, ww * v.w);
    }
}

// ---------------- Decode ----------------
__global__ __launch_bounds__(256) void decode_kernel(const float* __restrict__ z,
                                                     const int* __restrict__ ps,
                                                     const int* __restrict__ pd,
                                                     const float* __restrict__ Wlin,
                                                     float* __restrict__ out, int P) {
    const int lane = threadIdx.x & 63;
    const int wid = threadIdx.x >> 6;
    const int nwaves = (gridDim.x * blockDim.x) >> 6;

    float wa[8], wb[8];
#pragma unroll
    for (int i = 0; i < 8; ++i) {
        wa[i] = Wlin[(lane * 4) * 2 + i];
        wb[i] = Wlin[(NHID + lane * 4) * 2 + i];
    }

    for (int p = blockIdx.x * 4 + wid; p < P; p += nwaves) {
        int a = ps[p];
        int b = pd[p];
        float4 va = ((const float4*)(z + (long)a * NHID))[lane];
        float4 vb = ((const float4*)(z + (long)b * NHID))[lane];
        float acc0 = va.x * wa[0] + va.y * wa[2] + va.z * wa[4] + va.w * wa[6]
                   + vb.x * wb[0] + vb.y * wb[2] + vb.z * wb[4] + vb.w * wb[6];
        float acc1 = va.x * wa[1] + va.y * wa[3] + va.z * wa[5] + va.w * wa[7]
                   + vb.x * wb[1] + vb.y * wb[3] + vb.z * wb[5] + vb.w * wb[7];
#pragma unroll
        for (int off = 32; off > 0; off >>= 1) {
            acc0 += __shfl_down(acc0, off);
            acc1 += __shfl_down(acc1, off);
        }
        if (lane == 0) {
            out[(long)p * 2 + 0] = acc0;
            out[(long)p * 2 + 1] = acc1;
        }
    }
}

extern "C" void kernel_launch(void* const* d_in, const int* in_sizes, int n_in,
                              void* d_out, int out_size, void* d_ws, size_t ws_size,
                              hipStream_t stream) {
    (void)n_in; (void)out_size;
    const float* x    = (const float*)d_in[0];   // [N, 512]
    const int*   ei   = (const int*)d_in[1];     // [2, E]
    const float* ew   = (const float*)d_in[2];   // [E]
    const int*   pei  = (const int*)d_in[3];     // [2, P]
    const float* W1   = (const float*)d_in[4];   // [512, 256]
    const float* W2   = (const float*)d_in[5];   // [256, 256]
    const float* Wlin = (const float*)d_in[6];   // [512, 2]
    float* out = (float*)d_out;                  // [P, 2]

    const int E = in_sizes[2];
    const int P = in_sizes[3] / 2;
    const int N = in_sizes[0] / NFEAT;

    float* bufA = (float*)d_ws;                 // h1 then h2  [N,256]
    float* bufB = bufA + (size_t)N * NHID;      // z1 then z2  [N,256]
    int*   offsets = (int*)(bufB + (size_t)N * NHID);  // [N+1]
    int*   cursor  = offsets + (N + 1);                // [N] (counts, then running cursor)
    int*   ssrc    = cursor + N;                       // [E]
    float* sw      = (float*)(ssrc + E);               // [E]

    const size_t need = ((size_t)2 * N * NHID + (N + 1) + N + 2 * (size_t)E) * sizeof(float);
    const size_t zbytes = (size_t)N * NHID * sizeof(float);

    dim3 blk(256);
    dim3 gemm_grid((N + 63) / 64, NHID / 64);
    const int* src = ei;
    const int* dst = ei + E;

    if (ws_size >= need) {
        // ---- Build CSR by dst (once; reused for both layers) ----
        hipMemsetAsync(cursor, 0, (size_t)N * sizeof(int), stream);
        hist_kernel<<<1024, blk, 0, stream>>>(dst, cursor, E);
        scan_kernel<<<1, 1024, 0, stream>>>(cursor, offsets, cursor, N);
        sort_edges<<<1024, blk, 0, stream>>>(src, dst, ew, cursor, ssrc, sw, E);

        // ---- Layer 1 ----
        gemm_tiled<false><<<gemm_grid, blk, 0, stream>>>(x, W1, bufA, N, NHID, NFEAT);
        gather_conv<<<(N + 3) / 4, blk, 0, stream>>>(bufA, offsets, ssrc, sw, bufB, N);
        // ---- Layer 2 ----
        gemm_tiled<true><<<gemm_grid, blk, 0, stream>>>(bufB, W2, bufA, N, NHID, NHID);
        gather_conv<<<(N + 3) / 4, blk, 0, stream>>>(bufA, offsets, ssrc, sw, bufB, N);
    } else {
        // Fallback: atomic scatter path
        gemm_tiled<false><<<gemm_grid, blk, 0, stream>>>(x, W1, bufA, N, NHID, NFEAT);
        hipMemsetAsync(bufB, 0, zbytes, stream);
        scatter_conv<<<2048, blk, 0, stream>>>(bufA, src, dst, ew, bufB, E);
        gemm_tiled<true><<<gemm_grid, blk, 0, stream>>>(bufB, W2, bufA, N, NHID, NHID);
        hipMemsetAsync(bufB, 0, zbytes, stream);
        scatter_conv<<<2048, blk, 0, stream>>>(bufA, src, dst, ew, bufB, E);
    }

    // ---- Decode ----
    decode_kernel<<<(P + 3) / 4, blk, 0, stream>>>(bufB, pei, pei + P, Wlin, out, P);
}

// Round 3
// 505.705 us; speedup vs baseline: 11.3667x; 1.6471x over previous
//
#include <hip/hip_runtime.h>

#define NHID 256
#define NFEAT 512
#define BM 128
#define BN 128
#define BKE 32

using short8  = __attribute__((ext_vector_type(8))) short;
using ushort8v = __attribute__((ext_vector_type(8))) unsigned short;
using f32x4   = __attribute__((ext_vector_type(4))) float;

__device__ __forceinline__ float b2f(unsigned short u) {
    union { float f; unsigned v; } c;
    c.v = ((unsigned)u) << 16;
    return c.f;
}
__device__ __forceinline__ unsigned short f2b(float f) {
    union { float f; unsigned u; } c;
    c.f = f;
    unsigned r = c.u + 0x7fffu + ((c.u >> 16) & 1u);  // RNE
    return (unsigned short)(r >> 16);
}

// ---------------- convert x -> bf16 (8 floats/thread) ----------------
__global__ __launch_bounds__(256) void convert_bf16x8(const float* __restrict__ x,
                                                      unsigned short* __restrict__ xb,
                                                      long n8) {
    long i = (long)blockIdx.x * blockDim.x + threadIdx.x;
    const long stride = (long)gridDim.x * blockDim.x;
    for (; i < n8; i += stride) {
        float4 v0 = ((const float4*)x)[2 * i];
        float4 v1 = ((const float4*)x)[2 * i + 1];
        ushort8v o;
        o[0] = f2b(v0.x); o[1] = f2b(v0.y); o[2] = f2b(v0.z); o[3] = f2b(v0.w);
        o[4] = f2b(v1.x); o[5] = f2b(v1.y); o[6] = f2b(v1.z); o[7] = f2b(v1.w);
        ((ushort8v*)xb)[i] = o;
    }
}

// ---------------- W [K,N] -> WT bf16 [N,K] ----------------
__global__ __launch_bounds__(256) void transposeW(const float* __restrict__ W,
                                                  unsigned short* __restrict__ WT,
                                                  int K, int N) {
    int i = blockIdx.x * blockDim.x + threadIdx.x;
    if (i < K * N) {
        int k = i / N, n = i % N;
        WT[(size_t)n * K + k] = f2b(W[i]);
    }
}

// ---------------- MFMA GEMM: C[M,N] = A[M,K] @ BT[N,K]^T, all bf16, fp32 acc ----------------
__global__ __launch_bounds__(256) void gemm_mfma(const unsigned short* __restrict__ A,
                                                 const unsigned short* __restrict__ BT,
                                                 unsigned short* __restrict__ C,
                                                 int M, int N, int K) {
    __shared__ unsigned short As[BM * BKE];
    __shared__ unsigned short Bs[BN * BKE];
    const int tid = threadIdx.x;
    const int lane = tid & 63;
    const int wave = tid >> 6;
    const int wr = wave >> 1, wc = wave & 1;
    const int brow = blockIdx.x * BM;
    const int bcol = blockIdx.y * BN;

    const int a_row0 = tid >> 2;        // staged row (+64 for second issue)
    const int a_k = (tid & 3) * 8;      // k element offset within tile

    const int lrow = lane & 15;
    const int lk = (lane >> 4) * 8;

    f32x4 acc[4][4] = {};

    for (int k0 = 0; k0 < K; k0 += BKE) {
        short8 ar[2], br[2];
#pragma unroll
        for (int i = 0; i < 2; ++i) {
            int row = a_row0 + i * 64;
            int grow = brow + row; if (grow >= M) grow = M - 1;   // clamp (rows independent)
            ar[i] = *(const short8*)(A + (size_t)grow * K + k0 + a_k);
            br[i] = *(const short8*)(BT + (size_t)(bcol + row) * K + k0 + a_k);
        }
        __syncthreads();   // previous iter's LDS reads done
#pragma unroll
        for (int i = 0; i < 2; ++i) {
            int row = a_row0 + i * 64;
            *(short8*)(As + row * BKE + a_k) = ar[i];
            *(short8*)(Bs + row * BKE + a_k) = br[i];
        }
        __syncthreads();
        short8 a[4], b[4];
#pragma unroll
        for (int m = 0; m < 4; ++m)
            a[m] = *(const short8*)(As + (wr * 64 + m * 16 + lrow) * BKE + lk);
#pragma unroll
        for (int n = 0; n < 4; ++n)
            b[n] = *(const short8*)(Bs + (wc * 64 + n * 16 + lrow) * BKE + lk);
#pragma unroll
        for (int m = 0; m < 4; ++m)
#pragma unroll
            for (int n = 0; n < 4; ++n)
                acc[m][n] = __builtin_amdgcn_mfma_f32_16x16x32_bf16(a[m], b[n], acc[m][n], 0, 0, 0);
    }

#pragma unroll
    for (int m = 0; m < 4; ++m) {
#pragma unroll
        for (int r = 0; r < 4; ++r) {
            int row = brow + wr * 64 + m * 16 + (lane >> 4) * 4 + r;
            if (row < M) {
#pragma unroll
                for (int n = 0; n < 4; ++n) {
                    int col = bcol + wc * 64 + n * 16 + (lane & 15);
                    C[(size_t)row * N + col] = f2b(acc[m][n][r]);
                }
            }
        }
    }
}

// ---------------- CSR build ----------------
__global__ __launch_bounds__(256) void hist_kernel(const int* __restrict__ dst,
                                                   int* __restrict__ counts, int E) {
    for (int e = blockIdx.x * blockDim.x + threadIdx.x; e < E; e += gridDim.x * blockDim.x)
        atomicAdd(&counts[dst[e]], 1);
}

__global__ __launch_bounds__(1024) void scan_kernel(const int* __restrict__ counts,
                                                    int* __restrict__ offsets,
                                                    int* __restrict__ cursor, int n) {
    __shared__ int sums[1024];
    const int tid = threadIdx.x;
    const int chunk = (n + 1023) / 1024;
    const int begin = min(tid * chunk, n);
    const int end = min(begin + chunk, n);
    int s = 0;
    for (int i = begin; i < end; ++i) s += counts[i];
    sums[tid] = s;
    __syncthreads();
    for (int off = 1; off < 1024; off <<= 1) {
        int v = (tid >= off) ? sums[tid - off] : 0;
        __syncthreads();
        sums[tid] += v;
        __syncthreads();
    }
    int prefix = (tid == 0) ? 0 : sums[tid - 1];
    for (int i = begin; i < end; ++i) {
        int c = counts[i];
        offsets[i] = prefix;
        cursor[i] = prefix;
        prefix += c;
    }
    if (tid == 1023) offsets[n] = prefix;
}

__global__ __launch_bounds__(256) void sort_edges(const int* __restrict__ src,
                                                  const int* __restrict__ dst,
                                                  const float* __restrict__ w,
                                                  int* __restrict__ cursor,
                                                  int* __restrict__ ssrc,
                                                  float* __restrict__ sw, int E) {
    for (int e = blockIdx.x * blockDim.x + threadIdx.x; e < E; e += gridDim.x * blockDim.x) {
        int d = dst[e];
        int pos = atomicAdd(&cursor[d], 1);
        ssrc[pos] = src[e];
        sw[pos] = w[e];
    }
}

// ---------------- Gather conv (bf16 in/out, fp32 acc) ----------------
template <bool RELU>
__global__ __launch_bounds__(256) void gather_conv_b(const unsigned short* __restrict__ h,
                                                     const int* __restrict__ offsets,
                                                     const int* __restrict__ ssrc,
                                                     const float* __restrict__ sw,
                                                     unsigned short* __restrict__ z, int N) {
    const int lane = threadIdx.x & 63;
    const int wid = threadIdx.x >> 6;
    const int node = blockIdx.x * 4 + wid;
    if (node >= N) return;
    const int s0 = offsets[node];
    const int s1 = offsets[node + 1];
    float a0 = 0.f, a1 = 0.f, a2 = 0.f, a3 = 0.f;
    for (int i = s0; i < s1; ++i) {
        int s = ssrc[i];
        float ww = sw[i];
        ushort4 v = ((const ushort4*)(h + (size_t)s * NHID))[lane];
        a0 += ww * b2f(v.x);
        a1 += ww * b2f(v.y);
        a2 += ww * b2f(v.z);
        a3 += ww * b2f(v.w);
    }
    if (RELU) {
        a0 = fmaxf(a0, 0.f); a1 = fmaxf(a1, 0.f);
        a2 = fmaxf(a2, 0.f); a3 = fmaxf(a3, 0.f);
    }
    ushort4 o;
    o.x = f2b(a0); o.y = f2b(a1); o.z = f2b(a2); o.w = f2b(a3);
    ((ushort4*)(z + (size_t)node * NHID))[lane] = o;
}

// ---------------- Decode (bf16 z) ----------------
__global__ __launch_bounds__(256) void decode_b(const unsigned short* __restrict__ z,
                                                const int* __restrict__ ps,
                                                const int* __restrict__ pd,
                                                const float* __restrict__ Wlin,
                                                float* __restrict__ out, int P) {
    const int lane = threadIdx.x & 63;
    const int wid = threadIdx.x >> 6;
    const int nwaves = (gridDim.x * blockDim.x) >> 6;

    float wa[8], wb[8];
#pragma unroll
    for (int i = 0; i < 8; ++i) {
        wa[i] = Wlin[(lane * 4) * 2 + i];
        wb[i] = Wlin[(NHID + lane * 4) * 2 + i];
    }

    for (int p = blockIdx.x * 4 + wid; p < P; p += nwaves) {
        int a = ps[p];
        int b = pd[p];
        ushort4 va = ((const ushort4*)(z + (size_t)a * NHID))[lane];
        ushort4 vb = ((const ushort4*)(z + (size_t)b * NHID))[lane];
        float acc0 = b2f(va.x) * wa[0] + b2f(va.y) * wa[2] + b2f(va.z) * wa[4] + b2f(va.w) * wa[6]
                   + b2f(vb.x) * wb[0] + b2f(vb.y) * wb[2] + b2f(vb.z) * wb[4] + b2f(vb.w) * wb[6];
        float acc1 = b2f(va.x) * wa[1] + b2f(va.y) * wa[3] + b2f(va.z) * wa[5] + b2f(va.w) * wa[7]
                   + b2f(vb.x) * wb[1] + b2f(vb.y) * wb[3] + b2f(vb.z) * wb[5] + b2f(vb.w) * wb[7];
#pragma unroll
        for (int off = 32; off > 0; off >>= 1) {
            acc0 += __shfl_down(acc0, off);
            acc1 += __shfl_down(acc1, off);
        }
        if (lane == 0) {
            out[(long)p * 2 + 0] = acc0;
            out[(long)p * 2 + 1] = acc1;
        }
    }
}

// ================= fp32 fallback path (ws too small) =================
template <bool RELU>
__global__ __launch_bounds__(256) void gemm_tiled(const float* __restrict__ A,
                                                  const float* __restrict__ B,
                                                  float* __restrict__ C,
                                                  int M, int N, int K) {
    __shared__ float As[16][65];
    __shared__ float Bs[16][64];
    const int block_row = blockIdx.x * 64;
    const int block_col = blockIdx.y * 64;
    const int tid = threadIdx.x;
    const int tx = tid & 15;
    const int ty = tid >> 4;
    float c[4][4] = {};
    for (int k0 = 0; k0 < K; k0 += 16) {
#pragma unroll
        for (int i = 0; i < 4; ++i) {
            int idx = tid + i * 256;
            int kk = idx & 15;
            int m = idx >> 4;
            int row = block_row + m;
            float v = 0.f;
            if (row < M) v = A[(long)row * K + k0 + kk];
            if (RELU) v = fmaxf(v, 0.f);
            As[kk][m] = v;
        }
#pragma unroll
        for (int i = 0; i < 4; ++i) {
            int idx = tid + i * 256;
            int n = idx & 63;
            int kk = idx >> 6;
            Bs[kk][n] = B[(long)(k0 + kk) * N + block_col + n];
        }
        __syncthreads();
#pragma unroll
        for (int kk = 0; kk < 16; ++kk) {
            float a[4], b[4];
#pragma unroll
            for (int i = 0; i < 4; ++i) a[i] = As[kk][ty * 4 + i];
#pragma unroll
            for (int j = 0; j < 4; ++j) b[j] = Bs[kk][tx * 4 + j];
#pragma unroll
            for (int i = 0; i < 4; ++i)
#pragma unroll
                for (int j = 0; j < 4; ++j) c[i][j] += a[i] * b[j];
        }
        __syncthreads();
    }
#pragma unroll
    for (int i = 0; i < 4; ++i) {
        int row = block_row + ty * 4 + i;
        if (row < M) {
            float* cp = C + (long)row * N + block_col + tx * 4;
#pragma unroll
            for (int j = 0; j < 4; ++j) cp[j] = c[i][j];
        }
    }
}

__global__ __launch_bounds__(256) void scatter_conv(const float* __restrict__ h,
                                                    const int* __restrict__ src,
                                                    const int* __restrict__ dst,
                                                    const float* __restrict__ w,
                                                    float* __restrict__ z, int E) {
    const int lane = threadIdx.x & 63;
    const int wid = threadIdx.x >> 6;
    const int nwaves = (gridDim.x * blockDim.x) >> 6;
    for (int e = blockIdx.x * 4 + wid; e < E; e += nwaves) {
        int s = src[e];
        int d = dst[e];
        float ww = w[e];
        float4 v = ((const float4*)(h + (long)s * NHID))[lane];
        float* zp = z + (long)d * NHID + lane * 4;
        atomicAdd(zp + 0, ww * v.x);
        atomicAdd(zp + 1, ww * v.y);
        atomicAdd(zp + 2, ww * v.z);
        atomicAdd(zp + 3, ww * v.w);
    }
}

__global__ __launch_bounds__(256) void decode_f(const float* __restrict__ z,
                                                const int* __restrict__ ps,
                                                const int* __restrict__ pd,
                                                const float* __restrict__ Wlin,
                                                float* __restrict__ out, int P) {
    const int lane = threadIdx.x & 63;
    const int wid = threadIdx.x >> 6;
    const int nwaves = (gridDim.x * blockDim.x) >> 6;
    float wa[8], wb[8];
#pragma unroll
    for (int i = 0; i < 8; ++i) {
        wa[i] = Wlin[(lane * 4) * 2 + i];
        wb[i] = Wlin[(NHID + lane * 4) * 2 + i];
    }
    for (int p = blockIdx.x * 4 + wid; p < P; p += nwaves) {
        int a = ps[p];
        int b = pd[p];
        float4 va = ((const float4*)(z + (long)a * NHID))[lane];
        float4 vb = ((const float4*)(z + (long)b * NHID))[lane];
        float acc0 = va.x * wa[0] + va.y * wa[2] + va.z * wa[4] + va.w * wa[6]
                   + vb.x * wb[0] + vb.y * wb[2] + vb.z * wb[4] + vb.w * wb[6];
        float acc1 = va.x * wa[1] + va.y * wa[3] + va.z * wa[5] + va.w * wa[7]
                   + vb.x * wb[1] + vb.y * wb[3] + vb.z * wb[5] + vb.w * wb[7];
#pragma unroll
        for (int off = 32; off > 0; off >>= 1) {
            acc0 += __shfl_down(acc0, off);
            acc1 += __shfl_down(acc1, off);
        }
        if (lane == 0) {
            out[(long)p * 2 + 0] = acc0;
            out[(long)p * 2 + 1] = acc1;
        }
    }
}

extern "C" void kernel_launch(void* const* d_in, const int* in_sizes, int n_in,
                              void* d_out, int out_size, void* d_ws, size_t ws_size,
                              hipStream_t stream) {
    (void)n_in; (void)out_size;
    const float* x    = (const float*)d_in[0];   // [N, 512]
    const int*   ei   = (const int*)d_in[1];     // [2, E]
    const float* ew   = (const float*)d_in[2];   // [E]
    const int*   pei  = (const int*)d_in[3];     // [2, P]
    const float* W1   = (const float*)d_in[4];   // [512, 256]
    const float* W2   = (const float*)d_in[5];   // [256, 256]
    const float* Wlin = (const float*)d_in[6];   // [512, 2]
    float* out = (float*)d_out;                  // [P, 2]

    const int E = in_sizes[2];
    const int P = in_sizes[3] / 2;
    const int M = in_sizes[0] / NFEAT;           // nodes

    dim3 blk(256);
    const int* src = ei;
    const int* dst = ei + E;

    // bf16 path workspace layout
    unsigned short* xb = (unsigned short*)d_ws;               // [M,512] bf16
    unsigned short* hA = xb + (size_t)M * NFEAT;              // [M,256] bf16
    unsigned short* hB = hA + (size_t)M * NHID;               // [M,256] bf16
    int* offsets = (int*)(hB + (size_t)M * NHID);             // [M+1]
    int* cursor  = offsets + (M + 1);                          // [M]
    int* ssrc    = cursor + M;                                 // [E]
    float* sw    = (float*)(ssrc + E);                         // [E]
    const size_t need = (size_t)M * NFEAT * 2 + 2 * (size_t)M * NHID * 2
                      + ((size_t)M + 1) * 4 + (size_t)M * 4 + (size_t)E * 8;

    if (ws_size >= need) {
        // W transposes live in the tail-unused d_out region until decode overwrites it
        unsigned short* W1bT = (unsigned short*)d_out;        // [256,512] bf16 (256 KB)
        unsigned short* W2bT = W1bT + (size_t)NHID * NFEAT;   // [256,256] bf16 (128 KB)

        convert_bf16x8<<<2048, blk, 0, stream>>>(x, xb, (long)M * NFEAT / 8);
        transposeW<<<(NFEAT * NHID + 255) / 256, blk, 0, stream>>>(W1, W1bT, NFEAT, NHID);
        transposeW<<<(NHID * NHID + 255) / 256, blk, 0, stream>>>(W2, W2bT, NHID, NHID);

        hipMemsetAsync(cursor, 0, (size_t)M * sizeof(int), stream);
        hist_kernel<<<1024, blk, 0, stream>>>(dst, cursor, E);
        scan_kernel<<<1, 1024, 0, stream>>>(cursor, offsets, cursor, M);
        sort_edges<<<1024, blk, 0, stream>>>(src, dst, ew, cursor, ssrc, sw, E);

        dim3 g1((M + BM - 1) / BM, NHID / BN);
        gemm_mfma<<<g1, blk, 0, stream>>>(xb, W1bT, hA, M, NHID, NFEAT);
        gather_conv_b<true><<<(M + 3) / 4, blk, 0, stream>>>(hA, offsets, ssrc, sw, hB, M);
        gemm_mfma<<<g1, blk, 0, stream>>>(hB, W2bT, hA, M, NHID, NHID);
        gather_conv_b<false><<<(M + 3) / 4, blk, 0, stream>>>(hA, offsets, ssrc, sw, hB, M);
        decode_b<<<(P + 3) / 4, blk, 0, stream>>>(hB, pei, pei + P, Wlin, out, P);
    } else {
        // fp32 atomic fallback
        float* bufA = (float*)d_ws;
        float* bufB = bufA + (size_t)M * NHID;
        const size_t zbytes = (size_t)M * NHID * sizeof(float);
        dim3 gemm_grid((M + 63) / 64, NHID / 64);
        gemm_tiled<false><<<gemm_grid, blk, 0, stream>>>(x, W1, bufA, M, NHID, NFEAT);
        hipMemsetAsync(bufB, 0, zbytes, stream);
        scatter_conv<<<2048, blk, 0, stream>>>(bufA, src, dst, ew, bufB, E);
        gemm_tiled<true><<<gemm_grid, blk, 0, stream>>>(bufB, W2, bufA, M, NHID, NHID);
        hipMemsetAsync(bufB, 0, zbytes, stream);
        scatter_conv<<<2048, blk, 0, stream>>>(bufA, src, dst, ew, bufB, E);
        decode_f<<<(P + 3) / 4, blk, 0, stream>>>(bufB, pei, pei + P, Wlin, out, P);
    }
}

// Round 4
// 349.169 us; speedup vs baseline: 16.4625x; 1.4483x over previous
//
#include <hip/hip_runtime.h>

#define NHID 256
#define NFEAT 512
#define BM 128
#define BN 128
#define BKE 32

using short8  = __attribute__((ext_vector_type(8))) short;
using ushort8v = __attribute__((ext_vector_type(8))) unsigned short;
using f32x4   = __attribute__((ext_vector_type(4))) float;

__device__ __forceinline__ float b2f(unsigned short u) {
    union { float f; unsigned v; } c;
    c.v = ((unsigned)u) << 16;
    return c.f;
}
__device__ __forceinline__ unsigned short f2b(float f) {
    union { float f; unsigned u; } c;
    c.f = f;
    unsigned r = c.u + 0x7fffu + ((c.u >> 16) & 1u);  // RNE
    return (unsigned short)(r >> 16);
}

// ---------------- convert x -> bf16 (8 floats/thread) ----------------
__global__ __launch_bounds__(256) void convert_bf16x8(const float* __restrict__ x,
                                                      unsigned short* __restrict__ xb,
                                                      long n8) {
    long i = (long)blockIdx.x * blockDim.x + threadIdx.x;
    const long stride = (long)gridDim.x * blockDim.x;
    for (; i < n8; i += stride) {
        float4 v0 = ((const float4*)x)[2 * i];
        float4 v1 = ((const float4*)x)[2 * i + 1];
        ushort8v o;
        o[0] = f2b(v0.x); o[1] = f2b(v0.y); o[2] = f2b(v0.z); o[3] = f2b(v0.w);
        o[4] = f2b(v1.x); o[5] = f2b(v1.y); o[6] = f2b(v1.z); o[7] = f2b(v1.w);
        ((ushort8v*)xb)[i] = o;
    }
}

// ---------------- W [K,N] -> WT bf16 [N,K] ----------------
__global__ __launch_bounds__(256) void transposeW(const float* __restrict__ W,
                                                  unsigned short* __restrict__ WT,
                                                  int K, int N) {
    int i = blockIdx.x * blockDim.x + threadIdx.x;
    if (i < K * N) {
        int k = i / N, n = i % N;
        WT[(size_t)n * K + k] = f2b(W[i]);
    }
}

// ---------------- MFMA GEMM: C[M,N] = A[M,K] @ BT[N,K]^T, all bf16, fp32 acc ----------------
__global__ __launch_bounds__(256) void gemm_mfma(const unsigned short* __restrict__ A,
                                                 const unsigned short* __restrict__ BT,
                                                 unsigned short* __restrict__ C,
                                                 int M, int N, int K) {
    __shared__ unsigned short As[BM * BKE];
    __shared__ unsigned short Bs[BN * BKE];
    const int tid = threadIdx.x;
    const int lane = tid & 63;
    const int wave = tid >> 6;
    const int wr = wave >> 1, wc = wave & 1;
    const int brow = blockIdx.x * BM;
    const int bcol = blockIdx.y * BN;

    const int a_row0 = tid >> 2;
    const int a_k = (tid & 3) * 8;

    const int lrow = lane & 15;
    const int lk = (lane >> 4) * 8;

    f32x4 acc[4][4] = {};

    for (int k0 = 0; k0 < K; k0 += BKE) {
        short8 ar[2], br[2];
#pragma unroll
        for (int i = 0; i < 2; ++i) {
            int row = a_row0 + i * 64;
            int grow = brow + row; if (grow >= M) grow = M - 1;
            ar[i] = *(const short8*)(A + (size_t)grow * K + k0 + a_k);
            br[i] = *(const short8*)(BT + (size_t)(bcol + row) * K + k0 + a_k);
        }
        __syncthreads();
#pragma unroll
        for (int i = 0; i < 2; ++i) {
            int row = a_row0 + i * 64;
            *(short8*)(As + row * BKE + a_k) = ar[i];
            *(short8*)(Bs + row * BKE + a_k) = br[i];
        }
        __syncthreads();
        short8 a[4], b[4];
#pragma unroll
        for (int m = 0; m < 4; ++m)
            a[m] = *(const short8*)(As + (wr * 64 + m * 16 + lrow) * BKE + lk);
#pragma unroll
        for (int n = 0; n < 4; ++n)
            b[n] = *(const short8*)(Bs + (wc * 64 + n * 16 + lrow) * BKE + lk);
#pragma unroll
        for (int m = 0; m < 4; ++m)
#pragma unroll
            for (int n = 0; n < 4; ++n)
                acc[m][n] = __builtin_amdgcn_mfma_f32_16x16x32_bf16(a[m], b[n], acc[m][n], 0, 0, 0);
    }

#pragma unroll
    for (int m = 0; m < 4; ++m) {
#pragma unroll
        for (int r = 0; r < 4; ++r) {
            int row = brow + wr * 64 + m * 16 + (lane >> 4) * 4 + r;
            if (row < M) {
#pragma unroll
                for (int n = 0; n < 4; ++n) {
                    int col = bcol + wc * 64 + n * 16 + (lane & 15);
                    C[(size_t)row * N + col] = f2b(acc[m][n][r]);
                }
            }
        }
    }
}

// ---------------- CSR build ----------------
__global__ __launch_bounds__(256) void hist_kernel(const int* __restrict__ dst,
                                                   int* __restrict__ counts, int E) {
    for (int e = blockIdx.x * blockDim.x + threadIdx.x; e < E; e += gridDim.x * blockDim.x)
        atomicAdd(&counts[dst[e]], 1);
}

// Hierarchical scan, stage 1: per-block exclusive prefix of 1024 counts + block sum.
__global__ __launch_bounds__(1024) void scan_local(const int* __restrict__ counts,
                                                   int* __restrict__ local,
                                                   int* __restrict__ blocksums, int n) {
    __shared__ int s[1024];
    const int tid = threadIdx.x;
    const int idx = blockIdx.x * 1024 + tid;
    int v = (idx < n) ? counts[idx] : 0;
    s[tid] = v;
    __syncthreads();
    for (int off = 1; off < 1024; off <<= 1) {
        int t = (tid >= off) ? s[tid - off] : 0;
        __syncthreads();
        s[tid] += t;
        __syncthreads();
    }
    if (idx < n) local[idx] = s[tid] - v;          // exclusive prefix within block
    if (tid == 1023) blocksums[blockIdx.x] = s[1023];
}

// Stage 2: exclusive scan of block sums (nb <= 1024), in place.
__global__ __launch_bounds__(1024) void scan_sums(int* __restrict__ blocksums, int nb) {
    __shared__ int s[1024];
    const int tid = threadIdx.x;
    int v = (tid < nb) ? blocksums[tid] : 0;
    s[tid] = v;
    __syncthreads();
    for (int off = 1; off < 1024; off <<= 1) {
        int t = (tid >= off) ? s[tid - off] : 0;
        __syncthreads();
        s[tid] += t;
        __syncthreads();
    }
    if (tid < nb) blocksums[tid] = s[tid] - v;
}

// Stage 3: add block offset; fill offsets and cursor; offsets[n] = total (=E).
__global__ __launch_bounds__(256) void scan_finalize(int* __restrict__ offsets,
                                                     int* __restrict__ cursor,
                                                     const int* __restrict__ blockoffs,
                                                     int n, int total) {
    int idx = blockIdx.x * blockDim.x + threadIdx.x;
    if (idx < n) {
        int o = offsets[idx] + blockoffs[idx >> 10];
        offsets[idx] = o;
        cursor[idx] = o;
    }
    if (idx == 0) offsets[n] = total;
}

__global__ __launch_bounds__(256) void sort_edges(const int* __restrict__ src,
                                                  const int* __restrict__ dst,
                                                  const float* __restrict__ w,
                                                  int* __restrict__ cursor,
                                                  int* __restrict__ ssrc,
                                                  float* __restrict__ sw, int E) {
    for (int e = blockIdx.x * blockDim.x + threadIdx.x; e < E; e += gridDim.x * blockDim.x) {
        int d = dst[e];
        int pos = atomicAdd(&cursor[d], 1);
        ssrc[pos] = src[e];
        sw[pos] = w[e];
    }
}

// ---------------- Gather conv (bf16 in/out, fp32 acc), 4-deep MLP ----------------
template <bool RELU>
__global__ __launch_bounds__(256) void gather_conv_b(const unsigned short* __restrict__ h,
                                                     const int* __restrict__ offsets,
                                                     const int* __restrict__ ssrc,
                                                     const float* __restrict__ sw,
                                                     unsigned short* __restrict__ z, int N) {
    const int lane = threadIdx.x & 63;
    const int wid = threadIdx.x >> 6;
    const int node = blockIdx.x * 4 + wid;
    if (node >= N) return;
    const int s0 = offsets[node];
    const int s1 = offsets[node + 1];
    float a0 = 0.f, a1 = 0.f, a2 = 0.f, a3 = 0.f;
    int i = s0;
    for (; i + 4 <= s1; i += 4) {
        int sA = ssrc[i], sB = ssrc[i + 1], sC = ssrc[i + 2], sD = ssrc[i + 3];
        float wA = sw[i], wB = sw[i + 1], wC = sw[i + 2], wD = sw[i + 3];
        ushort4 vA = ((const ushort4*)(h + (size_t)sA * NHID))[lane];
        ushort4 vB = ((const ushort4*)(h + (size_t)sB * NHID))[lane];
        ushort4 vC = ((const ushort4*)(h + (size_t)sC * NHID))[lane];
        ushort4 vD = ((const ushort4*)(h + (size_t)sD * NHID))[lane];
        a0 += wA * b2f(vA.x) + wB * b2f(vB.x) + wC * b2f(vC.x) + wD * b2f(vD.x);
        a1 += wA * b2f(vA.y) + wB * b2f(vB.y) + wC * b2f(vC.y) + wD * b2f(vD.y);
        a2 += wA * b2f(vA.z) + wB * b2f(vB.z) + wC * b2f(vC.z) + wD * b2f(vD.z);
        a3 += wA * b2f(vA.w) + wB * b2f(vB.w) + wC * b2f(vC.w) + wD * b2f(vD.w);
    }
    for (; i < s1; ++i) {
        int s = ssrc[i];
        float ww = sw[i];
        ushort4 v = ((const ushort4*)(h + (size_t)s * NHID))[lane];
        a0 += ww * b2f(v.x);
        a1 += ww * b2f(v.y);
        a2 += ww * b2f(v.z);
        a3 += ww * b2f(v.w);
    }
    if (RELU) {
        a0 = fmaxf(a0, 0.f); a1 = fmaxf(a1, 0.f);
        a2 = fmaxf(a2, 0.f); a3 = fmaxf(a3, 0.f);
    }
    ushort4 o;
    o.x = f2b(a0); o.y = f2b(a1); o.z = f2b(a2); o.w = f2b(a3);
    ((ushort4*)(z + (size_t)node * NHID))[lane] = o;
}

// ---------------- Decode (bf16 z) ----------------
__global__ __launch_bounds__(256) void decode_b(const unsigned short* __restrict__ z,
                                                const int* __restrict__ ps,
                                                const int* __restrict__ pd,
                                                const float* __restrict__ Wlin,
                                                float* __restrict__ out, int P) {
    const int lane = threadIdx.x & 63;
    const int wid = threadIdx.x >> 6;
    const int nwaves = (gridDim.x * blockDim.x) >> 6;

    float wa[8], wb[8];
#pragma unroll
    for (int i = 0; i < 8; ++i) {
        wa[i] = Wlin[(lane * 4) * 2 + i];
        wb[i] = Wlin[(NHID + lane * 4) * 2 + i];
    }

    for (int p = blockIdx.x * 4 + wid; p < P; p += nwaves) {
        int a = ps[p];
        int b = pd[p];
        ushort4 va = ((const ushort4*)(z + (size_t)a * NHID))[lane];
        ushort4 vb = ((const ushort4*)(z + (size_t)b * NHID))[lane];
        float acc0 = b2f(va.x) * wa[0] + b2f(va.y) * wa[2] + b2f(va.z) * wa[4] + b2f(va.w) * wa[6]
                   + b2f(vb.x) * wb[0] + b2f(vb.y) * wb[2] + b2f(vb.z) * wb[4] + b2f(vb.w) * wb[6];
        float acc1 = b2f(va.x) * wa[1] + b2f(va.y) * wa[3] + b2f(va.z) * wa[5] + b2f(va.w) * wa[7]
                   + b2f(vb.x) * wb[1] + b2f(vb.y) * wb[3] + b2f(vb.z) * wb[5] + b2f(vb.w) * wb[7];
#pragma unroll
        for (int off = 32; off > 0; off >>= 1) {
            acc0 += __shfl_down(acc0, off);
            acc1 += __shfl_down(acc1, off);
        }
        if (lane == 0) {
            out[(long)p * 2 + 0] = acc0;
            out[(long)p * 2 + 1] = acc1;
        }
    }
}

// ================= fp32 fallback path (ws too small) =================
template <bool RELU>
__global__ __launch_bounds__(256) void gemm_tiled(const float* __restrict__ A,
                                                  const float* __restrict__ B,
                                                  float* __restrict__ C,
                                                  int M, int N, int K) {
    __shared__ float As[16][65];
    __shared__ float Bs[16][64];
    const int block_row = blockIdx.x * 64;
    const int block_col = blockIdx.y * 64;
    const int tid = threadIdx.x;
    const int tx = tid & 15;
    const int ty = tid >> 4;
    float c[4][4] = {};
    for (int k0 = 0; k0 < K; k0 += 16) {
#pragma unroll
        for (int i = 0; i < 4; ++i) {
            int idx = tid + i * 256;
            int kk = idx & 15;
            int m = idx >> 4;
            int row = block_row + m;
            float v = 0.f;
            if (row < M) v = A[(long)row * K + k0 + kk];
            if (RELU) v = fmaxf(v, 0.f);
            As[kk][m] = v;
        }
#pragma unroll
        for (int i = 0; i < 4; ++i) {
            int idx = tid + i * 256;
            int n = idx & 63;
            int kk = idx >> 6;
            Bs[kk][n] = B[(long)(k0 + kk) * N + block_col + n];
        }
        __syncthreads();
#pragma unroll
        for (int kk = 0; kk < 16; ++kk) {
            float a[4], b[4];
#pragma unroll
            for (int i = 0; i < 4; ++i) a[i] = As[kk][ty * 4 + i];
#pragma unroll
            for (int j = 0; j < 4; ++j) b[j] = Bs[kk][tx * 4 + j];
#pragma unroll
            for (int i = 0; i < 4; ++i)
#pragma unroll
                for (int j = 0; j < 4; ++j) c[i][j] += a[i] * b[j];
        }
        __syncthreads();
    }
#pragma unroll
    for (int i = 0; i < 4; ++i) {
        int row = block_row + ty * 4 + i;
        if (row < M) {
            float* cp = C + (long)row * N + block_col + tx * 4;
#pragma unroll
            for (int j = 0; j < 4; ++j) cp[j] = c[i][j];
        }
    }
}

__global__ __launch_bounds__(256) void scatter_conv(const float* __restrict__ h,
                                                    const int* __restrict__ src,
                                                    const int* __restrict__ dst,
                                                    const float* __restrict__ w,
                                                    float* __restrict__ z, int E) {
    const int lane = threadIdx.x & 63;
    const int wid = threadIdx.x >> 6;
    const int nwaves = (gridDim.x * blockDim.x) >> 6;
    for (int e = blockIdx.x * 4 + wid; e < E; e += nwaves) {
        int s = src[e];
        int d = dst[e];
        float ww = w[e];
        float4 v = ((const float4*)(h + (long)s * NHID))[lane];
        float* zp = z + (long)d * NHID + lane * 4;
        atomicAdd(zp + 0, ww * v.x);
        atomicAdd(zp + 1, ww * v.y);
        atomicAdd(zp + 2, ww * v.z);
        atomicAdd(zp + 3, ww * v.w);
    }
}

__global__ __launch_bounds__(256) void decode_f(const float* __restrict__ z,
                                                const int* __restrict__ ps,
                                                const int* __restrict__ pd,
                                                const float* __restrict__ Wlin,
                                                float* __restrict__ out, int P) {
    const int lane = threadIdx.x & 63;
    const int wid = threadIdx.x >> 6;
    const int nwaves = (gridDim.x * blockDim.x) >> 6;
    float wa[8], wb[8];
#pragma unroll
    for (int i = 0; i < 8; ++i) {
        wa[i] = Wlin[(lane * 4) * 2 + i];
        wb[i] = Wlin[(NHID + lane * 4) * 2 + i];
    }
    for (int p = blockIdx.x * 4 + wid; p < P; p += nwaves) {
        int a = ps[p];
        int b = pd[p];
        float4 va = ((const float4*)(z + (long)a * NHID))[lane];
        float4 vb = ((const float4*)(z + (long)b * NHID))[lane];
        float acc0 = va.x * wa[0] + va.y * wa[2] + va.z * wa[4] + va.w * wa[6]
                   + vb.x * wb[0] + vb.y * wb[2] + vb.z * wb[4] + vb.w * wb[6];
        float acc1 = va.x * wa[1] + va.y * wa[3] + va.z * wa[5] + va.w * wa[7]
                   + vb.x * wb[1] + vb.y * wb[3] + vb.z * wb[5] + vb.w * wb[7];
#pragma unroll
        for (int off = 32; off > 0; off >>= 1) {
            acc0 += __shfl_down(acc0, off);
            acc1 += __shfl_down(acc1, off);
        }
        if (lane == 0) {
            out[(long)p * 2 + 0] = acc0;
            out[(long)p * 2 + 1] = acc1;
        }
    }
}

extern "C" void kernel_launch(void* const* d_in, const int* in_sizes, int n_in,
                              void* d_out, int out_size, void* d_ws, size_t ws_size,
                              hipStream_t stream) {
    (void)n_in; (void)out_size;
    const float* x    = (const float*)d_in[0];   // [N, 512]
    const int*   ei   = (const int*)d_in[1];     // [2, E]
    const float* ew   = (const float*)d_in[2];   // [E]
    const int*   pei  = (const int*)d_in[3];     // [2, P]
    const float* W1   = (const float*)d_in[4];   // [512, 256]
    const float* W2   = (const float*)d_in[5];   // [256, 256]
    const float* Wlin = (const float*)d_in[6];   // [512, 2]
    float* out = (float*)d_out;                  // [P, 2]

    const int E = in_sizes[2];
    const int P = in_sizes[3] / 2;
    const int M = in_sizes[0] / NFEAT;           // nodes

    dim3 blk(256);
    const int* src = ei;
    const int* dst = ei + E;

    // bf16 path workspace layout
    unsigned short* xb = (unsigned short*)d_ws;               // [M,512] bf16
    unsigned short* hA = xb + (size_t)M * NFEAT;              // [M,256] bf16
    unsigned short* hB = hA + (size_t)M * NHID;               // [M,256] bf16
    int* offsets = (int*)(hB + (size_t)M * NHID);             // [M+1]
    int* cursor  = offsets + (M + 1);                          // [M]
    int* ssrc    = cursor + M;                                 // [E]
    float* sw    = (float*)(ssrc + E);                         // [E]
    int* blocksums = (int*)(sw + E);                           // [1024]
    const size_t need = (size_t)M * NFEAT * 2 + 2 * (size_t)M * NHID * 2
                      + ((size_t)M + 1) * 4 + (size_t)M * 4 + (size_t)E * 8 + 1024 * 4;

    if (ws_size >= need) {
        unsigned short* W1bT = (unsigned short*)d_out;        // [256,512] bf16 (256 KB)
        unsigned short* W2bT = W1bT + (size_t)NHID * NFEAT;   // [256,256] bf16 (128 KB)

        convert_bf16x8<<<2048, blk, 0, stream>>>(x, xb, (long)M * NFEAT / 8);
        transposeW<<<(NFEAT * NHID + 255) / 256, blk, 0, stream>>>(W1, W1bT, NFEAT, NHID);
        transposeW<<<(NHID * NHID + 255) / 256, blk, 0, stream>>>(W2, W2bT, NHID, NHID);

        // ---- CSR build with hierarchical scan ----
        const int nb = (M + 1023) / 1024;
        hipMemsetAsync(cursor, 0, (size_t)M * sizeof(int), stream);
        hist_kernel<<<1024, blk, 0, stream>>>(dst, cursor, E);
        scan_local<<<nb, 1024, 0, stream>>>(cursor, offsets, blocksums, M);
        scan_sums<<<1, 1024, 0, stream>>>(blocksums, nb);
        scan_finalize<<<(M + 255) / 256, blk, 0, stream>>>(offsets, cursor, blocksums, M, E);
        sort_edges<<<1024, blk, 0, stream>>>(src, dst, ew, cursor, ssrc, sw, E);

        dim3 g1((M + BM - 1) / BM, NHID / BN);
        gemm_mfma<<<g1, blk, 0, stream>>>(xb, W1bT, hA, M, NHID, NFEAT);
        gather_conv_b<true><<<(M + 3) / 4, blk, 0, stream>>>(hA, offsets, ssrc, sw, hB, M);
        gemm_mfma<<<g1, blk, 0, stream>>>(hB, W2bT, hA, M, NHID, NHID);
        gather_conv_b<false><<<(M + 3) / 4, blk, 0, stream>>>(hA, offsets, ssrc, sw, hB, M);
        decode_b<<<(P + 3) / 4, blk, 0, stream>>>(hB, pei, pei + P, Wlin, out, P);
    } else {
        // fp32 atomic fallback
        float* bufA = (float*)d_ws;
        float* bufB = bufA + (size_t)M * NHID;
        const size_t zbytes = (size_t)M * NHID * sizeof(float);
        dim3 gemm_grid((M + 63) / 64, NHID / 64);
        gemm_tiled<false><<<gemm_grid, blk, 0, stream>>>(x, W1, bufA, M, NHID, NFEAT);
        hipMemsetAsync(bufB, 0, zbytes, stream);
        scatter_conv<<<2048, blk, 0, stream>>>(bufA, src, dst, ew, bufB, E);
        gemm_tiled<true><<<gemm_grid, blk, 0, stream>>>(bufB, W2, bufA, M, NHID, NHID);
        hipMemsetAsync(bufB, 0, zbytes, stream);
        scatter_conv<<<2048, blk, 0, stream>>>(bufA, src, dst, ew, bufB, E);
        decode_f<<<(P + 3) / 4, blk, 0, stream>>>(bufB, pei, pei + P, Wlin, out, P);
    }
}

// Round 5
// 295.571 us; speedup vs baseline: 19.4477x; 1.1813x over previous
//
#include <hip/hip_runtime.h>

#define NHID 256
#define NFEAT 512
#define BM 128
#define BN 128
#define BKE 32

using short8  = __attribute__((ext_vector_type(8))) short;
using float8  = __attribute__((ext_vector_type(8))) float;
using f32x4   = __attribute__((ext_vector_type(4))) float;

__device__ __forceinline__ float b2f(unsigned short u) {
    union { float f; unsigned v; } c;
    c.v = ((unsigned)u) << 16;
    return c.f;
}
__device__ __forceinline__ unsigned short f2b(float f) {
    union { float f; unsigned u; } c;
    c.f = f;
    unsigned r = c.u + 0x7fffu + ((c.u >> 16) & 1u);  // RNE
    return (unsigned short)(r >> 16);
}
__device__ __forceinline__ unsigned short f2h(float f) {
    union { _Float16 h; unsigned short u; } c;
    c.h = (_Float16)f;
    return c.u;
}
__device__ __forceinline__ float h2f(unsigned short u) {
    union { _Float16 h; unsigned short u; } c;
    c.u = u;
    return (float)c.h;
}

// ---------------- W [K,N] -> WT bf16 [N,K] ----------------
__global__ __launch_bounds__(256) void transposeW(const float* __restrict__ W,
                                                  unsigned short* __restrict__ WT,
                                                  int K, int N) {
    int i = blockIdx.x * blockDim.x + threadIdx.x;
    if (i < K * N) {
        int k = i / N, n = i % N;
        WT[(size_t)n * K + k] = f2b(W[i]);
    }
}

// ---------------- MFMA GEMM: C[M,N] = A[M,K] @ BT[N,K]^T ----------------
// AT = float (fused fp32->bf16 convert on stage) or unsigned short (bf16).
template <typename AT>
__global__ __launch_bounds__(256) void gemm_mfma(const AT* __restrict__ A,
                                                 const unsigned short* __restrict__ BT,
                                                 unsigned short* __restrict__ C,
                                                 int M, int N, int K) {
    __shared__ unsigned short As[BM * BKE];
    __shared__ unsigned short Bs[BN * BKE];
    const int tid = threadIdx.x;
    const int lane = tid & 63;
    const int wave = tid >> 6;
    const int wr = wave >> 1, wc = wave & 1;
    const int brow = blockIdx.x * BM;
    const int bcol = blockIdx.y * BN;

    const int a_row0 = tid >> 2;
    const int a_k = (tid & 3) * 8;

    const int lrow = lane & 15;
    const int lk = (lane >> 4) * 8;

    f32x4 acc[4][4] = {};

    for (int k0 = 0; k0 < K; k0 += BKE) {
        short8 ar[2], br[2];
#pragma unroll
        for (int i = 0; i < 2; ++i) {
            int row = a_row0 + i * 64;
            int grow = brow + row; if (grow >= M) grow = M - 1;
            if constexpr (sizeof(AT) == 4) {
                float8 t = *(const float8*)(A + (size_t)grow * K + k0 + a_k);
                short8 v;
#pragma unroll
                for (int j = 0; j < 8; ++j) v[j] = (short)f2b(t[j]);
                ar[i] = v;
            } else {
                ar[i] = *(const short8*)(A + (size_t)grow * K + k0 + a_k);
            }
            br[i] = *(const short8*)(BT + (size_t)(bcol + row) * K + k0 + a_k);
        }
        __syncthreads();
#pragma unroll
        for (int i = 0; i < 2; ++i) {
            int row = a_row0 + i * 64;
            *(short8*)(As + row * BKE + a_k) = ar[i];
            *(short8*)(Bs + row * BKE + a_k) = br[i];
        }
        __syncthreads();
        short8 a[4], b[4];
#pragma unroll
        for (int m = 0; m < 4; ++m)
            a[m] = *(const short8*)(As + (wr * 64 + m * 16 + lrow) * BKE + lk);
#pragma unroll
        for (int n = 0; n < 4; ++n)
            b[n] = *(const short8*)(Bs + (wc * 64 + n * 16 + lrow) * BKE + lk);
#pragma unroll
        for (int m = 0; m < 4; ++m)
#pragma unroll
            for (int n = 0; n < 4; ++n)
                acc[m][n] = __builtin_amdgcn_mfma_f32_16x16x32_bf16(a[m], b[n], acc[m][n], 0, 0, 0);
    }

#pragma unroll
    for (int m = 0; m < 4; ++m) {
#pragma unroll
        for (int r = 0; r < 4; ++r) {
            int row = brow + wr * 64 + m * 16 + (lane >> 4) * 4 + r;
            if (row < M) {
#pragma unroll
                for (int n = 0; n < 4; ++n) {
                    int col = bcol + wc * 64 + n * 16 + (lane & 15);
                    C[(size_t)row * N + col] = f2b(acc[m][n][r]);
                }
            }
        }
    }
}

// ---------------- CSR build ----------------
__global__ __launch_bounds__(256) void hist_kernel(const int* __restrict__ dst,
                                                   int* __restrict__ counts, int E) {
    for (int e = blockIdx.x * blockDim.x + threadIdx.x; e < E; e += gridDim.x * blockDim.x)
        atomicAdd(&counts[dst[e]], 1);
}

__global__ __launch_bounds__(1024) void scan_local(const int* __restrict__ counts,
                                                   int* __restrict__ local,
                                                   int* __restrict__ blocksums, int n) {
    __shared__ int s[1024];
    const int tid = threadIdx.x;
    const int idx = blockIdx.x * 1024 + tid;
    int v = (idx < n) ? counts[idx] : 0;
    s[tid] = v;
    __syncthreads();
    for (int off = 1; off < 1024; off <<= 1) {
        int t = (tid >= off) ? s[tid - off] : 0;
        __syncthreads();
        s[tid] += t;
        __syncthreads();
    }
    if (idx < n) local[idx] = s[tid] - v;
    if (tid == 1023) blocksums[blockIdx.x] = s[1023];
}

__global__ __launch_bounds__(1024) void scan_sums(int* __restrict__ blocksums, int nb) {
    __shared__ int s[1024];
    const int tid = threadIdx.x;
    int v = (tid < nb) ? blocksums[tid] : 0;
    s[tid] = v;
    __syncthreads();
    for (int off = 1; off < 1024; off <<= 1) {
        int t = (tid >= off) ? s[tid - off] : 0;
        __syncthreads();
        s[tid] += t;
        __syncthreads();
    }
    if (tid < nb) blocksums[tid] = s[tid] - v;
}

__global__ __launch_bounds__(256) void scan_finalize(int* __restrict__ offsets,
                                                     int* __restrict__ cursor,
                                                     const int* __restrict__ blockoffs,
                                                     int n, int total) {
    int idx = blockIdx.x * blockDim.x + threadIdx.x;
    if (idx < n) {
        int o = offsets[idx] + blockoffs[idx >> 10];
        offsets[idx] = o;
        cursor[idx] = o;
    }
    if (idx == 0) offsets[n] = total;
}

// Packed payload: (fp16 weight << 16) | u16 src. One 4B scattered store per edge.
__global__ __launch_bounds__(256) void sort_edges_pk(const int* __restrict__ src,
                                                     const int* __restrict__ dst,
                                                     const float* __restrict__ w,
                                                     int* __restrict__ cursor,
                                                     unsigned* __restrict__ pk, int E) {
    for (int e = blockIdx.x * blockDim.x + threadIdx.x; e < E; e += gridDim.x * blockDim.x) {
        int d = dst[e];
        int pos = atomicAdd(&cursor[d], 1);
        pk[pos] = ((unsigned)f2h(w[e]) << 16) | (unsigned)src[e];
    }
}

// ---------------- Gather conv layer-1 (bf16 h -> relu -> bf16 z) ----------------
__global__ __launch_bounds__(256) void gather_conv_pk(const unsigned short* __restrict__ h,
                                                      const int* __restrict__ offsets,
                                                      const unsigned* __restrict__ pk,
                                                      unsigned short* __restrict__ z, int N) {
    const int lane = threadIdx.x & 63;
    const int wid = threadIdx.x >> 6;
    const int node = blockIdx.x * 4 + wid;
    if (node >= N) return;
    const int s0 = offsets[node];
    const int s1 = offsets[node + 1];
    float a0 = 0.f, a1 = 0.f, a2 = 0.f, a3 = 0.f;
    int i = s0;
    for (; i + 4 <= s1; i += 4) {
        unsigned qA = pk[i], qB = pk[i + 1], qC = pk[i + 2], qD = pk[i + 3];
        float wA = h2f(qA >> 16), wB = h2f(qB >> 16), wC = h2f(qC >> 16), wD = h2f(qD >> 16);
        ushort4 vA = ((const ushort4*)(h + (size_t)(qA & 0xffffu) * NHID))[lane];
        ushort4 vB = ((const ushort4*)(h + (size_t)(qB & 0xffffu) * NHID))[lane];
        ushort4 vC = ((const ushort4*)(h + (size_t)(qC & 0xffffu) * NHID))[lane];
        ushort4 vD = ((const ushort4*)(h + (size_t)(qD & 0xffffu) * NHID))[lane];
        a0 += wA * b2f(vA.x) + wB * b2f(vB.x) + wC * b2f(vC.x) + wD * b2f(vD.x);
        a1 += wA * b2f(vA.y) + wB * b2f(vB.y) + wC * b2f(vC.y) + wD * b2f(vD.y);
        a2 += wA * b2f(vA.z) + wB * b2f(vB.z) + wC * b2f(vC.z) + wD * b2f(vD.z);
        a3 += wA * b2f(vA.w) + wB * b2f(vB.w) + wC * b2f(vC.w) + wD * b2f(vD.w);
    }
    for (; i < s1; ++i) {
        unsigned q = pk[i];
        float ww = h2f(q >> 16);
        ushort4 v = ((const ushort4*)(h + (size_t)(q & 0xffffu) * NHID))[lane];
        a0 += ww * b2f(v.x);
        a1 += ww * b2f(v.y);
        a2 += ww * b2f(v.z);
        a3 += ww * b2f(v.w);
    }
    a0 = fmaxf(a0, 0.f); a1 = fmaxf(a1, 0.f);
    a2 = fmaxf(a2, 0.f); a3 = fmaxf(a3, 0.f);
    ushort4 o;
    o.x = f2b(a0); o.y = f2b(a1); o.z = f2b(a2); o.w = f2b(a3);
    ((ushort4*)(z + (size_t)node * NHID))[lane] = o;
}

// ---------------- Gather conv layer-2 fused with Wlin projection ----------------
// za[n] = z2[n] @ Wlin[0:256], zb[n] = z2[n] @ Wlin[256:512]  (z2 never materialized)
__global__ __launch_bounds__(256) void gather_wlin_pk(const unsigned short* __restrict__ h,
                                                      const int* __restrict__ offsets,
                                                      const unsigned* __restrict__ pk,
                                                      const float* __restrict__ Wlin,
                                                      float2* __restrict__ za,
                                                      float2* __restrict__ zb, int N) {
    const int lane = threadIdx.x & 63;
    const int wid = threadIdx.x >> 6;
    const int node = blockIdx.x * 4 + wid;
    if (node >= N) return;

    // Per-lane Wlin rows 4l..4l+3 (top half) and 256+4l.. (bottom half)
    float wt[8], wbm[8];
#pragma unroll
    for (int i = 0; i < 8; ++i) {
        wt[i]  = Wlin[(lane * 4) * 2 + i];
        wbm[i] = Wlin[(NHID + lane * 4) * 2 + i];
    }

    const int s0 = offsets[node];
    const int s1 = offsets[node + 1];
    float a0 = 0.f, a1 = 0.f, a2 = 0.f, a3 = 0.f;
    int i = s0;
    for (; i + 4 <= s1; i += 4) {
        unsigned qA = pk[i], qB = pk[i + 1], qC = pk[i + 2], qD = pk[i + 3];
        float wA = h2f(qA >> 16), wB = h2f(qB >> 16), wC = h2f(qC >> 16), wD = h2f(qD >> 16);
        ushort4 vA = ((const ushort4*)(h + (size_t)(qA & 0xffffu) * NHID))[lane];
        ushort4 vB = ((const ushort4*)(h + (size_t)(qB & 0xffffu) * NHID))[lane];
        ushort4 vC = ((const ushort4*)(h + (size_t)(qC & 0xffffu) * NHID))[lane];
        ushort4 vD = ((const ushort4*)(h + (size_t)(qD & 0xffffu) * NHID))[lane];
        a0 += wA * b2f(vA.x) + wB * b2f(vB.x) + wC * b2f(vC.x) + wD * b2f(vD.x);
        a1 += wA * b2f(vA.y) + wB * b2f(vB.y) + wC * b2f(vC.y) + wD * b2f(vD.y);
        a2 += wA * b2f(vA.z) + wB * b2f(vB.z) + wC * b2f(vC.z) + wD * b2f(vD.z);
        a3 += wA * b2f(vA.w) + wB * b2f(vB.w) + wC * b2f(vC.w) + wD * b2f(vD.w);
    }
    for (; i < s1; ++i) {
        unsigned q = pk[i];
        float ww = h2f(q >> 16);
        ushort4 v = ((const ushort4*)(h + (size_t)(q & 0xffffu) * NHID))[lane];
        a0 += ww * b2f(v.x);
        a1 += ww * b2f(v.y);
        a2 += ww * b2f(v.z);
        a3 += ww * b2f(v.w);
    }

    float pa0 = a0 * wt[0] + a1 * wt[2] + a2 * wt[4] + a3 * wt[6];
    float pa1 = a0 * wt[1] + a1 * wt[3] + a2 * wt[5] + a3 * wt[7];
    float pb0 = a0 * wbm[0] + a1 * wbm[2] + a2 * wbm[4] + a3 * wbm[6];
    float pb1 = a0 * wbm[1] + a1 * wbm[3] + a2 * wbm[5] + a3 * wbm[7];
#pragma unroll
    for (int off = 32; off > 0; off >>= 1) {
        pa0 += __shfl_down(pa0, off);
        pa1 += __shfl_down(pa1, off);
        pb0 += __shfl_down(pb0, off);
        pb1 += __shfl_down(pb1, off);
    }
    if (lane == 0) {
        za[node] = {pa0, pa1};
        zb[node] = {pb0, pb1};
    }
}

// ---------------- Decode: out[p] = za[ps[p]] + zb[pd[p]] ----------------
__global__ __launch_bounds__(256) void decode_pairs(const float2* __restrict__ za,
                                                    const float2* __restrict__ zb,
                                                    const int* __restrict__ ps,
                                                    const int* __restrict__ pd,
                                                    float2* __restrict__ out, int P) {
    int p = blockIdx.x * blockDim.x + threadIdx.x;
    if (p < P) {
        float2 va = za[ps[p]];
        float2 vb = zb[pd[p]];
        out[p] = {va.x + vb.x, va.y + vb.y};
    }
}

// ================= fp32 fallback path (ws too small or M > 65535) =================
template <bool RELU>
__global__ __launch_bounds__(256) void gemm_tiled(const float* __restrict__ A,
                                                  const float* __restrict__ B,
                                                  float* __restrict__ C,
                                                  int M, int N, int K) {
    __shared__ float As[16][65];
    __shared__ float Bs[16][64];
    const int block_row = blockIdx.x * 64;
    const int block_col = blockIdx.y * 64;
    const int tid = threadIdx.x;
    const int tx = tid & 15;
    const int ty = tid >> 4;
    float c[4][4] = {};
    for (int k0 = 0; k0 < K; k0 += 16) {
#pragma unroll
        for (int i = 0; i < 4; ++i) {
            int idx = tid + i * 256;
            int kk = idx & 15;
            int m = idx >> 4;
            int row = block_row + m;
            float v = 0.f;
            if (row < M) v = A[(long)row * K + k0 + kk];
            if (RELU) v = fmaxf(v, 0.f);
            As[kk][m] = v;
        }
#pragma unroll
        for (int i = 0; i < 4; ++i) {
            int idx = tid + i * 256;
            int n = idx & 63;
            int kk = idx >> 6;
            Bs[kk][n] = B[(long)(k0 + kk) * N + block_col + n];
        }
        __syncthreads();
#pragma unroll
        for (int kk = 0; kk < 16; ++kk) {
            float a[4], b[4];
#pragma unroll
            for (int i = 0; i < 4; ++i) a[i] = As[kk][ty * 4 + i];
#pragma unroll
            for (int j = 0; j < 4; ++j) b[j] = Bs[kk][tx * 4 + j];
#pragma unroll
            for (int i = 0; i < 4; ++i)
#pragma unroll
                for (int j = 0; j < 4; ++j) c[i][j] += a[i] * b[j];
        }
        __syncthreads();
    }
#pragma unroll
    for (int i = 0; i < 4; ++i) {
        int row = block_row + ty * 4 + i;
        if (row < M) {
            float* cp = C + (long)row * N + block_col + tx * 4;
#pragma unroll
            for (int j = 0; j < 4; ++j) cp[j] = c[i][j];
        }
    }
}

__global__ __launch_bounds__(256) void scatter_conv(const float* __restrict__ h,
                                                    const int* __restrict__ src,
                                                    const int* __restrict__ dst,
                                                    const float* __restrict__ w,
                                                    float* __restrict__ z, int E) {
    const int lane = threadIdx.x & 63;
    const int wid = threadIdx.x >> 6;
    const int nwaves = (gridDim.x * blockDim.x) >> 6;
    for (int e = blockIdx.x * 4 + wid; e < E; e += nwaves) {
        int s = src[e];
        int d = dst[e];
        float ww = w[e];
        float4 v = ((const float4*)(h + (long)s * NHID))[lane];
        float* zp = z + (long)d * NHID + lane * 4;
        atomicAdd(zp + 0, ww * v.x);
        atomicAdd(zp + 1, ww * v.y);
        atomicAdd(zp + 2, ww * v.z);
        atomicAdd(zp + 3, ww * v.w);
    }
}

__global__ __launch_bounds__(256) void decode_f(const float* __restrict__ z,
                                                const int* __restrict__ ps,
                                                const int* __restrict__ pd,
                                                const float* __restrict__ Wlin,
                                                float* __restrict__ out, int P) {
    const int lane = threadIdx.x & 63;
    const int wid = threadIdx.x >> 6;
    const int nwaves = (gridDim.x * blockDim.x) >> 6;
    float wa[8], wb[8];
#pragma unroll
    for (int i = 0; i < 8; ++i) {
        wa[i] = Wlin[(lane * 4) * 2 + i];
        wb[i] = Wlin[(NHID + lane * 4) * 2 + i];
    }
    for (int p = blockIdx.x * 4 + wid; p < P; p += nwaves) {
        int a = ps[p];
        int b = pd[p];
        float4 va = ((const float4*)(z + (long)a * NHID))[lane];
        float4 vb = ((const float4*)(z + (long)b * NHID))[lane];
        float acc0 = va.x * wa[0] + va.y * wa[2] + va.z * wa[4] + va.w * wa[6]
                   + vb.x * wb[0] + vb.y * wb[2] + vb.z * wb[4] + vb.w * wb[6];
        float acc1 = va.x * wa[1] + va.y * wa[3] + va.z * wa[5] + va.w * wa[7]
                   + vb.x * wb[1] + vb.y * wb[3] + vb.z * wb[5] + vb.w * wb[7];
#pragma unroll
        for (int off = 32; off > 0; off >>= 1) {
            acc0 += __shfl_down(acc0, off);
            acc1 += __shfl_down(acc1, off);
        }
        if (lane == 0) {
            out[(long)p * 2 + 0] = acc0;
            out[(long)p * 2 + 1] = acc1;
        }
    }
}

extern "C" void kernel_launch(void* const* d_in, const int* in_sizes, int n_in,
                              void* d_out, int out_size, void* d_ws, size_t ws_size,
                              hipStream_t stream) {
    (void)n_in; (void)out_size;
    const float* x    = (const float*)d_in[0];   // [M, 512]
    const int*   ei   = (const int*)d_in[1];     // [2, E]
    const float* ew   = (const float*)d_in[2];   // [E]
    const int*   pei  = (const int*)d_in[3];     // [2, P]
    const float* W1   = (const float*)d_in[4];   // [512, 256]
    const float* W2   = (const float*)d_in[5];   // [256, 256]
    const float* Wlin = (const float*)d_in[6];   // [512, 2]
    float* out = (float*)d_out;                  // [P, 2]

    const int E = in_sizes[2];
    const int P = in_sizes[3] / 2;
    const int M = in_sizes[0] / NFEAT;

    dim3 blk(256);
    const int* src = ei;
    const int* dst = ei + E;

    // workspace layout (bf16 path)
    unsigned short* hA = (unsigned short*)d_ws;               // [M,256] bf16
    unsigned short* hB = hA + (size_t)M * NHID;               // [M,256] bf16
    int* offsets = (int*)(hB + (size_t)M * NHID);             // [M+1]
    int* cursor  = offsets + (M + 1);                          // [M]
    unsigned* pk = (unsigned*)(cursor + M);                    // [E] packed (f16 w | u16 src)
    int* blocksums = (int*)(pk + E);                           // [1024]
    float2* za = (float2*)(blocksums + 1024);                  // [M]
    float2* zb = za + M;                                       // [M]
    const size_t need = 2 * (size_t)M * NHID * 2 + ((size_t)2 * M + 1) * 4
                      + (size_t)E * 4 + 1024 * 4 + (size_t)M * 2 * 8;

    if (ws_size >= need && M <= 65535) {
        unsigned short* W1bT = (unsigned short*)d_out;        // [256,512] bf16 (256 KB)
        unsigned short* W2bT = W1bT + (size_t)NHID * NFEAT;   // [256,256] bf16 (128 KB)

        transposeW<<<(NFEAT * NHID + 255) / 256, blk, 0, stream>>>(W1, W1bT, NFEAT, NHID);
        transposeW<<<(NHID * NHID + 255) / 256, blk, 0, stream>>>(W2, W2bT, NHID, NHID);

        // ---- CSR build ----
        const int nb = (M + 1023) / 1024;
        hipMemsetAsync(cursor, 0, (size_t)M * sizeof(int), stream);
        hist_kernel<<<1024, blk, 0, stream>>>(dst, cursor, E);
        scan_local<<<nb, 1024, 0, stream>>>(cursor, offsets, blocksums, M);
        scan_sums<<<1, 1024, 0, stream>>>(blocksums, nb);
        scan_finalize<<<(M + 255) / 256, blk, 0, stream>>>(offsets, cursor, blocksums, M, E);
        sort_edges_pk<<<1024, blk, 0, stream>>>(src, dst, ew, cursor, pk, E);

        // ---- Layer 1: hA = x(bf16-converted) @ W1 ----
        dim3 g1((M + BM - 1) / BM, NHID / BN);
        gemm_mfma<float><<<g1, blk, 0, stream>>>(x, W1bT, hA, M, NHID, NFEAT);
        gather_conv_pk<<<(M + 3) / 4, blk, 0, stream>>>(hA, offsets, pk, hB, M);
        // ---- Layer 2 + fused Wlin projection ----
        gemm_mfma<unsigned short><<<g1, blk, 0, stream>>>(hB, W2bT, hA, M, NHID, NHID);
        gather_wlin_pk<<<(M + 3) / 4, blk, 0, stream>>>(hA, offsets, pk, Wlin, za, zb, M);
        // ---- Decode ----
        decode_pairs<<<(P + 255) / 256, blk, 0, stream>>>(za, zb, pei, pei + P, (float2*)out, P);
    } else {
        // fp32 atomic fallback
        float* bufA = (float*)d_ws;
        float* bufB = bufA + (size_t)M * NHID;
        const size_t zbytes = (size_t)M * NHID * sizeof(float);
        dim3 gemm_grid((M + 63) / 64, NHID / 64);
        gemm_tiled<false><<<gemm_grid, blk, 0, stream>>>(x, W1, bufA, M, NHID, NFEAT);
        hipMemsetAsync(bufB, 0, zbytes, stream);
        scatter_conv<<<2048, blk, 0, stream>>>(bufA, src, dst, ew, bufB, E);
        gemm_tiled<true><<<gemm_grid, blk, 0, stream>>>(bufB, W2, bufA, M, NHID, NHID);
        hipMemsetAsync(bufB, 0, zbytes, stream);
        scatter_conv<<<2048, blk, 0, stream>>>(bufA, src, dst, ew, bufB, E);
        decode_f<<<(P + 3) / 4, blk, 0, stream>>>(bufB, pei, pei + P, Wlin, out, P);
    }
}

// Round 6
// 281.929 us; speedup vs baseline: 20.3887x; 1.0484x over previous
//
#include <hip/hip_runtime.h>
#include <type_traits>

#define NHID 256
#define NFEAT 512
#define BM 128
#define BN 128
#define BKE 32

using short8  = __attribute__((ext_vector_type(8))) short;
using float8  = __attribute__((ext_vector_type(8))) float;
using f32x4   = __attribute__((ext_vector_type(4))) float;

__device__ __forceinline__ float b2f(unsigned short u) {
    union { float f; unsigned v; } c;
    c.v = ((unsigned)u) << 16;
    return c.f;
}
__device__ __forceinline__ unsigned short f2b(float f) {
    union { float f; unsigned u; } c;
    c.f = f;
    unsigned r = c.u + 0x7fffu + ((c.u >> 16) & 1u);  // RNE
    return (unsigned short)(r >> 16);
}
__device__ __forceinline__ unsigned short f2h(float f) {
    union { _Float16 h; unsigned short u; } c;
    c.h = (_Float16)f;
    return c.u;
}
__device__ __forceinline__ float h2f(unsigned short u) {
    union { _Float16 h; unsigned short u; } c;
    c.u = u;
    return (float)c.h;
}

// ---------------- both W transposes in one launch ----------------
__global__ __launch_bounds__(256) void transposeW2(const float* __restrict__ W1,
                                                   const float* __restrict__ W2,
                                                   unsigned short* __restrict__ W1bT,
                                                   unsigned short* __restrict__ W2bT) {
    int i = blockIdx.x * blockDim.x + threadIdx.x;
    const int t1 = NFEAT * NHID;
    if (i < t1) {
        int k = i >> 8, n = i & 255;
        W1bT[(size_t)n * NFEAT + k] = f2b(W1[i]);
    } else {
        int j = i - t1;
        if (j < NHID * NHID) {
            int k = j >> 8, n = j & 255;
            W2bT[(size_t)n * NHID + k] = f2b(W2[j]);
        }
    }
}

// ---------------- MFMA GEMM: C[M,N] = A[M,K] @ BT[N,K]^T ----------------
// Double-buffered LDS, 1 barrier per K-step, padded LDS rows (bank-conflict-free-ish).
// AT = float (fused fp32->bf16 convert on stage) or unsigned short (bf16).
template <typename AT>
__global__ __launch_bounds__(256) void gemm_mfma(const AT* __restrict__ A,
                                                 const unsigned short* __restrict__ BT,
                                                 unsigned short* __restrict__ C,
                                                 int M, int N, int K) {
    constexpr int LDT = BKE + 8;  // 40 shorts = 80 B = 20 dwords row stride -> 2-way max
    __shared__ unsigned short As[2][BM * LDT];
    __shared__ unsigned short Bs[2][BN * LDT];
    const int tid = threadIdx.x;
    const int lane = tid & 63;
    const int wave = tid >> 6;
    const int wr = wave >> 1, wc = wave & 1;
    const int brow = blockIdx.x * BM;
    const int bcol = blockIdx.y * BN;

    const int a_row0 = tid >> 2;        // 0..63 (+64 on second issue)
    const int a_k = (tid & 3) * 8;      // 0,8,16,24

    const int lrow = lane & 15;
    const int lk = (lane >> 4) * 8;

    using StageA = typename std::conditional<sizeof(AT) == 4, float8, short8>::type;

    f32x4 acc[4][4] = {};
    const int nt = K / BKE;

    StageA pa[2];
    short8 pb[2];

    // ---- prologue: load + stage tile 0 ----
#pragma unroll
    for (int i = 0; i < 2; ++i) {
        int row = a_row0 + i * 64;
        int grow = brow + row; if (grow >= M) grow = M - 1;
        pa[i] = *(const StageA*)(A + (size_t)grow * K + a_k);
        pb[i] = *(const short8*)(BT + (size_t)(bcol + row) * K + a_k);
    }
#pragma unroll
    for (int i = 0; i < 2; ++i) {
        int row = a_row0 + i * 64;
        short8 av;
        if constexpr (sizeof(AT) == 4) {
#pragma unroll
            for (int j = 0; j < 8; ++j) av[j] = (short)f2b(pa[i][j]);
        } else {
            av = pa[i];
        }
        *(short8*)(&As[0][row * LDT + a_k]) = av;
        *(short8*)(&Bs[0][row * LDT + a_k]) = pb[i];
    }
    __syncthreads();

    int p = 0;
    for (int t = 0; t < nt; ++t) {
        // ---- prefetch tile t+1 into registers (latency hidden by MFMAs below) ----
        if (t + 1 < nt) {
            const int k0 = (t + 1) * BKE;
#pragma unroll
            for (int i = 0; i < 2; ++i) {
                int row = a_row0 + i * 64;
                int grow = brow + row; if (grow >= M) grow = M - 1;
                pa[i] = *(const StageA*)(A + (size_t)grow * K + k0 + a_k);
                pb[i] = *(const short8*)(BT + (size_t)(bcol + row) * K + k0 + a_k);
            }
        }
        // ---- compute tile t from LDS[p] ----
        short8 a[4], b[4];
#pragma unroll
        for (int m = 0; m < 4; ++m)
            a[m] = *(const short8*)(&As[p][(wr * 64 + m * 16 + lrow) * LDT + lk]);
#pragma unroll
        for (int n = 0; n < 4; ++n)
            b[n] = *(const short8*)(&Bs[p][(wc * 64 + n * 16 + lrow) * LDT + lk]);
#pragma unroll
        for (int m = 0; m < 4; ++m)
#pragma unroll
            for (int n = 0; n < 4; ++n)
                acc[m][n] = __builtin_amdgcn_mfma_f32_16x16x32_bf16(a[m], b[n], acc[m][n], 0, 0, 0);
        // ---- stage tile t+1 into LDS[p^1] ----
        if (t + 1 < nt) {
#pragma unroll
            for (int i = 0; i < 2; ++i) {
                int row = a_row0 + i * 64;
                short8 av;
                if constexpr (sizeof(AT) == 4) {
#pragma unroll
                    for (int j = 0; j < 8; ++j) av[j] = (short)f2b(pa[i][j]);
                } else {
                    av = pa[i];
                }
                *(short8*)(&As[p ^ 1][row * LDT + a_k]) = av;
                *(short8*)(&Bs[p ^ 1][row * LDT + a_k]) = pb[i];
            }
        }
        __syncthreads();
        p ^= 1;
    }

#pragma unroll
    for (int m = 0; m < 4; ++m) {
#pragma unroll
        for (int r = 0; r < 4; ++r) {
            int row = brow + wr * 64 + m * 16 + (lane >> 4) * 4 + r;
            if (row < M) {
#pragma unroll
                for (int n = 0; n < 4; ++n) {
                    int col = bcol + wc * 64 + n * 16 + (lane & 15);
                    C[(size_t)row * N + col] = f2b(acc[m][n][r]);
                }
            }
        }
    }
}

// ---------------- CSR build ----------------
__global__ __launch_bounds__(256) void hist_kernel(const int* __restrict__ dst,
                                                   int* __restrict__ counts, int E) {
    for (int e = blockIdx.x * blockDim.x + threadIdx.x; e < E; e += gridDim.x * blockDim.x)
        atomicAdd(&counts[dst[e]], 1);
}

__global__ __launch_bounds__(1024) void scan_local(const int* __restrict__ counts,
                                                   int* __restrict__ local,
                                                   int* __restrict__ blocksums, int n) {
    __shared__ int s[1024];
    const int tid = threadIdx.x;
    const int idx = blockIdx.x * 1024 + tid;
    int v = (idx < n) ? counts[idx] : 0;
    s[tid] = v;
    __syncthreads();
    for (int off = 1; off < 1024; off <<= 1) {
        int t = (tid >= off) ? s[tid - off] : 0;
        __syncthreads();
        s[tid] += t;
        __syncthreads();
    }
    if (idx < n) local[idx] = s[tid] - v;
    if (tid == 1023) blocksums[blockIdx.x] = s[1023];
}

__global__ __launch_bounds__(1024) void scan_sums(int* __restrict__ blocksums, int nb) {
    __shared__ int s[1024];
    const int tid = threadIdx.x;
    int v = (tid < nb) ? blocksums[tid] : 0;
    s[tid] = v;
    __syncthreads();
    for (int off = 1; off < 1024; off <<= 1) {
        int t = (tid >= off) ? s[tid - off] : 0;
        __syncthreads();
        s[tid] += t;
        __syncthreads();
    }
    if (tid < nb) blocksums[tid] = s[tid] - v;
}

__global__ __launch_bounds__(256) void scan_finalize(int* __restrict__ offsets,
                                                     int* __restrict__ cursor,
                                                     const int* __restrict__ blockoffs,
                                                     int n, int total) {
    int idx = blockIdx.x * blockDim.x + threadIdx.x;
    if (idx < n) {
        int o = offsets[idx] + blockoffs[idx >> 10];
        offsets[idx] = o;
        cursor[idx] = o;
    }
    if (idx == 0) offsets[n] = total;
}

// Packed payload: (fp16 weight << 16) | u16 src. One 4B scattered store per edge.
__global__ __launch_bounds__(256) void sort_edges_pk(const int* __restrict__ src,
                                                     const int* __restrict__ dst,
                                                     const float* __restrict__ w,
                                                     int* __restrict__ cursor,
                                                     unsigned* __restrict__ pk, int E) {
    for (int e = blockIdx.x * blockDim.x + threadIdx.x; e < E; e += gridDim.x * blockDim.x) {
        int d = dst[e];
        int pos = atomicAdd(&cursor[d], 1);
        pk[pos] = ((unsigned)f2h(w[e]) << 16) | (unsigned)src[e];
    }
}

// ---------------- Gather conv layer-1 (bf16 h -> relu -> bf16 z) ----------------
__global__ __launch_bounds__(256) void gather_conv_pk(const unsigned short* __restrict__ h,
                                                      const int* __restrict__ offsets,
                                                      const unsigned* __restrict__ pk,
                                                      unsigned short* __restrict__ z, int N) {
    const int lane = threadIdx.x & 63;
    const int wid = threadIdx.x >> 6;
    const int node = blockIdx.x * 4 + wid;
    if (node >= N) return;
    const int s0 = offsets[node];
    const int s1 = offsets[node + 1];
    float a0 = 0.f, a1 = 0.f, a2 = 0.f, a3 = 0.f;
    int i = s0;
    for (; i + 4 <= s1; i += 4) {
        unsigned qA = pk[i], qB = pk[i + 1], qC = pk[i + 2], qD = pk[i + 3];
        float wA = h2f(qA >> 16), wB = h2f(qB >> 16), wC = h2f(qC >> 16), wD = h2f(qD >> 16);
        ushort4 vA = ((const ushort4*)(h + (size_t)(qA & 0xffffu) * NHID))[lane];
        ushort4 vB = ((const ushort4*)(h + (size_t)(qB & 0xffffu) * NHID))[lane];
        ushort4 vC = ((const ushort4*)(h + (size_t)(qC & 0xffffu) * NHID))[lane];
        ushort4 vD = ((const ushort4*)(h + (size_t)(qD & 0xffffu) * NHID))[lane];
        a0 += wA * b2f(vA.x) + wB * b2f(vB.x) + wC * b2f(vC.x) + wD * b2f(vD.x);
        a1 += wA * b2f(vA.y) + wB * b2f(vB.y) + wC * b2f(vC.y) + wD * b2f(vD.y);
        a2 += wA * b2f(vA.z) + wB * b2f(vB.z) + wC * b2f(vC.z) + wD * b2f(vD.z);
        a3 += wA * b2f(vA.w) + wB * b2f(vB.w) + wC * b2f(vC.w) + wD * b2f(vD.w);
    }
    for (; i < s1; ++i) {
        unsigned q = pk[i];
        float ww = h2f(q >> 16);
        ushort4 v = ((const ushort4*)(h + (size_t)(q & 0xffffu) * NHID))[lane];
        a0 += ww * b2f(v.x);
        a1 += ww * b2f(v.y);
        a2 += ww * b2f(v.z);
        a3 += ww * b2f(v.w);
    }
    a0 = fmaxf(a0, 0.f); a1 = fmaxf(a1, 0.f);
    a2 = fmaxf(a2, 0.f); a3 = fmaxf(a3, 0.f);
    ushort4 o;
    o.x = f2b(a0); o.y = f2b(a1); o.z = f2b(a2); o.w = f2b(a3);
    ((ushort4*)(z + (size_t)node * NHID))[lane] = o;
}

// ---------------- Gather conv layer-2 fused with Wlin projection ----------------
__global__ __launch_bounds__(256) void gather_wlin_pk(const unsigned short* __restrict__ h,
                                                      const int* __restrict__ offsets,
                                                      const unsigned* __restrict__ pk,
                                                      const float* __restrict__ Wlin,
                                                      float2* __restrict__ za,
                                                      float2* __restrict__ zb, int N) {
    const int lane = threadIdx.x & 63;
    const int wid = threadIdx.x >> 6;
    const int node = blockIdx.x * 4 + wid;
    if (node >= N) return;

    float wt[8], wbm[8];
#pragma unroll
    for (int i = 0; i < 8; ++i) {
        wt[i]  = Wlin[(lane * 4) * 2 + i];
        wbm[i] = Wlin[(NHID + lane * 4) * 2 + i];
    }

    const int s0 = offsets[node];
    const int s1 = offsets[node + 1];
    float a0 = 0.f, a1 = 0.f, a2 = 0.f, a3 = 0.f;
    int i = s0;
    for (; i + 4 <= s1; i += 4) {
        unsigned qA = pk[i], qB = pk[i + 1], qC = pk[i + 2], qD = pk[i + 3];
        float wA = h2f(qA >> 16), wB = h2f(qB >> 16), wC = h2f(qC >> 16), wD = h2f(qD >> 16);
        ushort4 vA = ((const ushort4*)(h + (size_t)(qA & 0xffffu) * NHID))[lane];
        ushort4 vB = ((const ushort4*)(h + (size_t)(qB & 0xffffu) * NHID))[lane];
        ushort4 vC = ((const ushort4*)(h + (size_t)(qC & 0xffffu) * NHID))[lane];
        ushort4 vD = ((const ushort4*)(h + (size_t)(qD & 0xffffu) * NHID))[lane];
        a0 += wA * b2f(vA.x) + wB * b2f(vB.x) + wC * b2f(vC.x) + wD * b2f(vD.x);
        a1 += wA * b2f(vA.y) + wB * b2f(vB.y) + wC * b2f(vC.y) + wD * b2f(vD.y);
        a2 += wA * b2f(vA.z) + wB * b2f(vB.z) + wC * b2f(vC.z) + wD * b2f(vD.z);
        a3 += wA * b2f(vA.w) + wB * b2f(vB.w) + wC * b2f(vC.w) + wD * b2f(vD.w);
    }
    for (; i < s1; ++i) {
        unsigned q = pk[i];
        float ww = h2f(q >> 16);
        ushort4 v = ((const ushort4*)(h + (size_t)(q & 0xffffu) * NHID))[lane];
        a0 += ww * b2f(v.x);
        a1 += ww * b2f(v.y);
        a2 += ww * b2f(v.z);
        a3 += ww * b2f(v.w);
    }

    float pa0 = a0 * wt[0] + a1 * wt[2] + a2 * wt[4] + a3 * wt[6];
    float pa1 = a0 * wt[1] + a1 * wt[3] + a2 * wt[5] + a3 * wt[7];
    float pb0 = a0 * wbm[0] + a1 * wbm[2] + a2 * wbm[4] + a3 * wbm[6];
    float pb1 = a0 * wbm[1] + a1 * wbm[3] + a2 * wbm[5] + a3 * wbm[7];
#pragma unroll
    for (int off = 32; off > 0; off >>= 1) {
        pa0 += __shfl_down(pa0, off);
        pa1 += __shfl_down(pa1, off);
        pb0 += __shfl_down(pb0, off);
        pb1 += __shfl_down(pb1, off);
    }
    if (lane == 0) {
        za[node] = {pa0, pa1};
        zb[node] = {pb0, pb1};
    }
}

// ---------------- Decode: out[p] = za[ps[p]] + zb[pd[p]] ----------------
__global__ __launch_bounds__(256) void decode_pairs(const float2* __restrict__ za,
                                                    const float2* __restrict__ zb,
                                                    const int* __restrict__ ps,
                                                    const int* __restrict__ pd,
                                                    float2* __restrict__ out, int P) {
    int p = blockIdx.x * blockDim.x + threadIdx.x;
    if (p < P) {
        float2 va = za[ps[p]];
        float2 vb = zb[pd[p]];
        out[p] = {va.x + vb.x, va.y + vb.y};
    }
}

// ================= fp32 fallback path (ws too small or M > 65535) =================
template <bool RELU>
__global__ __launch_bounds__(256) void gemm_tiled(const float* __restrict__ A,
                                                  const float* __restrict__ B,
                                                  float* __restrict__ C,
                                                  int M, int N, int K) {
    __shared__ float As[16][65];
    __shared__ float Bs[16][64];
    const int block_row = blockIdx.x * 64;
    const int block_col = blockIdx.y * 64;
    const int tid = threadIdx.x;
    const int tx = tid & 15;
    const int ty = tid >> 4;
    float c[4][4] = {};
    for (int k0 = 0; k0 < K; k0 += 16) {
#pragma unroll
        for (int i = 0; i < 4; ++i) {
            int idx = tid + i * 256;
            int kk = idx & 15;
            int m = idx >> 4;
            int row = block_row + m;
            float v = 0.f;
            if (row < M) v = A[(long)row * K + k0 + kk];
            if (RELU) v = fmaxf(v, 0.f);
            As[kk][m] = v;
        }
#pragma unroll
        for (int i = 0; i < 4; ++i) {
            int idx = tid + i * 256;
            int n = idx & 63;
            int kk = idx >> 6;
            Bs[kk][n] = B[(long)(k0 + kk) * N + block_col + n];
        }
        __syncthreads();
#pragma unroll
        for (int kk = 0; kk < 16; ++kk) {
            float a[4], b[4];
#pragma unroll
            for (int i = 0; i < 4; ++i) a[i] = As[kk][ty * 4 + i];
#pragma unroll
            for (int j = 0; j < 4; ++j) b[j] = Bs[kk][tx * 4 + j];
#pragma unroll
            for (int i = 0; i < 4; ++i)
#pragma unroll
                for (int j = 0; j < 4; ++j) c[i][j] += a[i] * b[j];
        }
        __syncthreads();
    }
#pragma unroll
    for (int i = 0; i < 4; ++i) {
        int row = block_row + ty * 4 + i;
        if (row < M) {
            float* cp = C + (long)row * N + block_col + tx * 4;
#pragma unroll
            for (int j = 0; j < 4; ++j) cp[j] = c[i][j];
        }
    }
}

__global__ __launch_bounds__(256) void scatter_conv(const float* __restrict__ h,
                                                    const int* __restrict__ src,
                                                    const int* __restrict__ dst,
                                                    const float* __restrict__ w,
                                                    float* __restrict__ z, int E) {
    const int lane = threadIdx.x & 63;
    const int wid = threadIdx.x >> 6;
    const int nwaves = (gridDim.x * blockDim.x) >> 6;
    for (int e = blockIdx.x * 4 + wid; e < E; e += nwaves) {
        int s = src[e];
        int d = dst[e];
        float ww = w[e];
        float4 v = ((const float4*)(h + (long)s * NHID))[lane];
        float* zp = z + (long)d * NHID + lane * 4;
        atomicAdd(zp + 0, ww * v.x);
        atomicAdd(zp + 1, ww * v.y);
        atomicAdd(zp + 2, ww * v.z);
        atomicAdd(zp + 3, ww * v.w);
    }
}

__global__ __launch_bounds__(256) void decode_f(const float* __restrict__ z,
                                                const int* __restrict__ ps,
                                                const int* __restrict__ pd,
                                                const float* __restrict__ Wlin,
                                                float* __restrict__ out, int P) {
    const int lane = threadIdx.x & 63;
    const int wid = threadIdx.x >> 6;
    const int nwaves = (gridDim.x * blockDim.x) >> 6;
    float wa[8], wb[8];
#pragma unroll
    for (int i = 0; i < 8; ++i) {
        wa[i] = Wlin[(lane * 4) * 2 + i];
        wb[i] = Wlin[(NHID + lane * 4) * 2 + i];
    }
    for (int p = blockIdx.x * 4 + wid; p < P; p += nwaves) {
        int a = ps[p];
        int b = pd[p];
        float4 va = ((const float4*)(z + (long)a * NHID))[lane];
        float4 vb = ((const float4*)(z + (long)b * NHID))[lane];
        float acc0 = va.x * wa[0] + va.y * wa[2] + va.z * wa[4] + va.w * wa[6]
                   + vb.x * wb[0] + vb.y * wb[2] + vb.z * wb[4] + vb.w * wb[6];
        float acc1 = va.x * wa[1] + va.y * wa[3] + va.z * wa[5] + va.w * wa[7]
                   + vb.x * wb[1] + vb.y * wb[3] + vb.z * wb[5] + vb.w * wb[7];
#pragma unroll
        for (int off = 32; off > 0; off >>= 1) {
            acc0 += __shfl_down(acc0, off);
            acc1 += __shfl_down(acc1, off);
        }
        if (lane == 0) {
            out[(long)p * 2 + 0] = acc0;
            out[(long)p * 2 + 1] = acc1;
        }
    }
}

extern "C" void kernel_launch(void* const* d_in, const int* in_sizes, int n_in,
                              void* d_out, int out_size, void* d_ws, size_t ws_size,
                              hipStream_t stream) {
    (void)n_in; (void)out_size;
    const float* x    = (const float*)d_in[0];   // [M, 512]
    const int*   ei   = (const int*)d_in[1];     // [2, E]
    const float* ew   = (const float*)d_in[2];   // [E]
    const int*   pei  = (const int*)d_in[3];     // [2, P]
    const float* W1   = (const float*)d_in[4];   // [512, 256]
    const float* W2   = (const float*)d_in[5];   // [256, 256]
    const float* Wlin = (const float*)d_in[6];   // [512, 2]
    float* out = (float*)d_out;                  // [P, 2]

    const int E = in_sizes[2];
    const int P = in_sizes[3] / 2;
    const int M = in_sizes[0] / NFEAT;

    dim3 blk(256);
    const int* src = ei;
    const int* dst = ei + E;

    // workspace layout (bf16 path)
    unsigned short* hA = (unsigned short*)d_ws;               // [M,256] bf16
    unsigned short* hB = hA + (size_t)M * NHID;               // [M,256] bf16
    int* offsets = (int*)(hB + (size_t)M * NHID);             // [M+1]
    int* cursor  = offsets + (M + 1);                          // [M]
    unsigned* pk = (unsigned*)(cursor + M);                    // [E] packed (f16 w | u16 src)
    int* blocksums = (int*)(pk + E);                           // [1024]
    float2* za = (float2*)(blocksums + 1024);                  // [M]
    float2* zb = za + M;                                       // [M]
    const size_t need = 2 * (size_t)M * NHID * 2 + ((size_t)2 * M + 1) * 4
                      + (size_t)E * 4 + 1024 * 4 + (size_t)M * 2 * 8;

    if (ws_size >= need && M <= 65535) {
        unsigned short* W1bT = (unsigned short*)d_out;        // [256,512] bf16 (256 KB)
        unsigned short* W2bT = W1bT + (size_t)NHID * NFEAT;   // [256,256] bf16 (128 KB)

        transposeW2<<<(NFEAT * NHID + NHID * NHID + 255) / 256, blk, 0, stream>>>(W1, W2, W1bT, W2bT);

        // ---- CSR build ----
        const int nb = (M + 1023) / 1024;
        hipMemsetAsync(cursor, 0, (size_t)M * sizeof(int), stream);
        hist_kernel<<<1024, blk, 0, stream>>>(dst, cursor, E);
        scan_local<<<nb, 1024, 0, stream>>>(cursor, offsets, blocksums, M);
        scan_sums<<<1, 1024, 0, stream>>>(blocksums, nb);
        scan_finalize<<<(M + 255) / 256, blk, 0, stream>>>(offsets, cursor, blocksums, M, E);
        sort_edges_pk<<<1024, blk, 0, stream>>>(src, dst, ew, cursor, pk, E);

        // ---- Layer 1: hA = x(bf16-converted) @ W1 ----
        dim3 g1((M + BM - 1) / BM, NHID / BN);
        gemm_mfma<float><<<g1, blk, 0, stream>>>(x, W1bT, hA, M, NHID, NFEAT);
        gather_conv_pk<<<(M + 3) / 4, blk, 0, stream>>>(hA, offsets, pk, hB, M);
        // ---- Layer 2 + fused Wlin projection ----
        gemm_mfma<unsigned short><<<g1, blk, 0, stream>>>(hB, W2bT, hA, M, NHID, NHID);
        gather_wlin_pk<<<(M + 3) / 4, blk, 0, stream>>>(hA, offsets, pk, Wlin, za, zb, M);
        // ---- Decode ----
        decode_pairs<<<(P + 255) / 256, blk, 0, stream>>>(za, zb, pei, pei + P, (float2*)out, P);
    } else {
        // fp32 atomic fallback
        float* bufA = (float*)d_ws;
        float* bufB = bufA + (size_t)M * NHID;
        const size_t zbytes = (size_t)M * NHID * sizeof(float);
        dim3 gemm_grid((M + 63) / 64, NHID / 64);
        gemm_tiled<false><<<gemm_grid, blk, 0, stream>>>(x, W1, bufA, M, NHID, NFEAT);
        hipMemsetAsync(bufB, 0, zbytes, stream);
        scatter_conv<<<2048, blk, 0, stream>>>(bufA, src, dst, ew, bufB, E);
        gemm_tiled<true><<<gemm_grid, blk, 0, stream>>>(bufB, W2, bufA, M, NHID, NHID);
        hipMemsetAsync(bufB, 0, zbytes, stream);
        scatter_conv<<<2048, blk, 0, stream>>>(bufA, src, dst, ew, bufB, E);
        decode_f<<<(P + 3) / 4, blk, 0, stream>>>(bufB, pei, pei + P, Wlin, out, P);
    }
}

// Round 7
// 275.055 us; speedup vs baseline: 20.8983x; 1.0250x over previous
//
#include <hip/hip_runtime.h>
#include <type_traits>

#define NHID 256
#define NFEAT 512
#define BM 128
#define BN 128
#define BKE 32

using short8  = __attribute__((ext_vector_type(8))) short;
using float8  = __attribute__((ext_vector_type(8))) float;
using f32x4   = __attribute__((ext_vector_type(4))) float;

__device__ __forceinline__ float b2f(unsigned short u) {
    union { float f; unsigned v; } c;
    c.v = ((unsigned)u) << 16;
    return c.f;
}
__device__ __forceinline__ unsigned short f2b(float f) {
    union { float f; unsigned u; } c;
    c.f = f;
    unsigned r = c.u + 0x7fffu + ((c.u >> 16) & 1u);  // RNE
    return (unsigned short)(r >> 16);
}
__device__ __forceinline__ unsigned short f2h(float f) {
    union { _Float16 h; unsigned short u; } c;
    c.h = (_Float16)f;
    return c.u;
}
__device__ __forceinline__ float h2f(unsigned short u) {
    union { _Float16 h; unsigned short u; } c;
    c.u = u;
    return (float)c.h;
}

// ---------------- both W transposes in one launch ----------------
__global__ __launch_bounds__(256) void transposeW2(const float* __restrict__ W1,
                                                   const float* __restrict__ W2,
                                                   unsigned short* __restrict__ W1bT,
                                                   unsigned short* __restrict__ W2bT) {
    int i = blockIdx.x * blockDim.x + threadIdx.x;
    const int t1 = NFEAT * NHID;
    if (i < t1) {
        int k = i >> 8, n = i & 255;
        W1bT[(size_t)n * NFEAT + k] = f2b(W1[i]);
    } else {
        int j = i - t1;
        if (j < NHID * NHID) {
            int k = j >> 8, n = j & 255;
            W2bT[(size_t)n * NHID + k] = f2b(W2[j]);
        }
    }
}

// ---------------- MFMA GEMM: C[M,N] = A[M,K] @ BT[N,K]^T ----------------
// Double-buffered LDS, 1 barrier per K-step, padded LDS rows.
template <typename AT>
__global__ __launch_bounds__(256) void gemm_mfma(const AT* __restrict__ A,
                                                 const unsigned short* __restrict__ BT,
                                                 unsigned short* __restrict__ C,
                                                 int M, int N, int K) {
    constexpr int LDT = BKE + 8;  // 40 shorts = 80 B row stride -> 2-way max conflict
    __shared__ unsigned short As[2][BM * LDT];
    __shared__ unsigned short Bs[2][BN * LDT];
    const int tid = threadIdx.x;
    const int lane = tid & 63;
    const int wave = tid >> 6;
    const int wr = wave >> 1, wc = wave & 1;
    const int brow = blockIdx.x * BM;
    const int bcol = blockIdx.y * BN;

    const int a_row0 = tid >> 2;
    const int a_k = (tid & 3) * 8;

    const int lrow = lane & 15;
    const int lk = (lane >> 4) * 8;

    using StageA = typename std::conditional<sizeof(AT) == 4, float8, short8>::type;

    f32x4 acc[4][4] = {};
    const int nt = K / BKE;

    StageA pa[2];
    short8 pb[2];

#pragma unroll
    for (int i = 0; i < 2; ++i) {
        int row = a_row0 + i * 64;
        int grow = brow + row; if (grow >= M) grow = M - 1;
        pa[i] = *(const StageA*)(A + (size_t)grow * K + a_k);
        pb[i] = *(const short8*)(BT + (size_t)(bcol + row) * K + a_k);
    }
#pragma unroll
    for (int i = 0; i < 2; ++i) {
        int row = a_row0 + i * 64;
        short8 av;
        if constexpr (sizeof(AT) == 4) {
#pragma unroll
            for (int j = 0; j < 8; ++j) av[j] = (short)f2b(pa[i][j]);
        } else {
            av = pa[i];
        }
        *(short8*)(&As[0][row * LDT + a_k]) = av;
        *(short8*)(&Bs[0][row * LDT + a_k]) = pb[i];
    }
    __syncthreads();

    int p = 0;
    for (int t = 0; t < nt; ++t) {
        if (t + 1 < nt) {
            const int k0 = (t + 1) * BKE;
#pragma unroll
            for (int i = 0; i < 2; ++i) {
                int row = a_row0 + i * 64;
                int grow = brow + row; if (grow >= M) grow = M - 1;
                pa[i] = *(const StageA*)(A + (size_t)grow * K + k0 + a_k);
                pb[i] = *(const short8*)(BT + (size_t)(bcol + row) * K + k0 + a_k);
            }
        }
        short8 a[4], b[4];
#pragma unroll
        for (int m = 0; m < 4; ++m)
            a[m] = *(const short8*)(&As[p][(wr * 64 + m * 16 + lrow) * LDT + lk]);
#pragma unroll
        for (int n = 0; n < 4; ++n)
            b[n] = *(const short8*)(&Bs[p][(wc * 64 + n * 16 + lrow) * LDT + lk]);
#pragma unroll
        for (int m = 0; m < 4; ++m)
#pragma unroll
            for (int n = 0; n < 4; ++n)
                acc[m][n] = __builtin_amdgcn_mfma_f32_16x16x32_bf16(a[m], b[n], acc[m][n], 0, 0, 0);
        if (t + 1 < nt) {
#pragma unroll
            for (int i = 0; i < 2; ++i) {
                int row = a_row0 + i * 64;
                short8 av;
                if constexpr (sizeof(AT) == 4) {
#pragma unroll
                    for (int j = 0; j < 8; ++j) av[j] = (short)f2b(pa[i][j]);
                } else {
                    av = pa[i];
                }
                *(short8*)(&As[p ^ 1][row * LDT + a_k]) = av;
                *(short8*)(&Bs[p ^ 1][row * LDT + a_k]) = pb[i];
            }
        }
        __syncthreads();
        p ^= 1;
    }

#pragma unroll
    for (int m = 0; m < 4; ++m) {
#pragma unroll
        for (int r = 0; r < 4; ++r) {
            int row = brow + wr * 64 + m * 16 + (lane >> 4) * 4 + r;
            if (row < M) {
#pragma unroll
                for (int n = 0; n < 4; ++n) {
                    int col = bcol + wc * 64 + n * 16 + (lane & 15);
                    C[(size_t)row * N + col] = f2b(acc[m][n][r]);
                }
            }
        }
    }
}

// ---------------- CSR build, XCD-range-partitioned ----------------
// Group g = blockIdx & 7 (round-robin -> XCD g) owns dst range [g*span, min((g+1)*span, M)).
// All atomics/stores for a dst land on one XCD's L2 -> no cross-XCD line bouncing.
__global__ __launch_bounds__(256) void hist_part(const int* __restrict__ dst,
                                                 int* __restrict__ counts,
                                                 int E, int span, int M) {
    const int g = blockIdx.x & 7;
    const int rank = blockIdx.x >> 3;
    const int nrank = gridDim.x >> 3;
    const int lo = g * span;
    const int hi = min(lo + span, M);
    for (int e = rank * blockDim.x + threadIdx.x; e < E; e += nrank * blockDim.x) {
        int d = dst[e];
        if (d >= lo && d < hi) atomicAdd(&counts[d], 1);
    }
}

__global__ __launch_bounds__(1024) void scan_local(const int* __restrict__ counts,
                                                   int* __restrict__ local,
                                                   int* __restrict__ blocksums, int n) {
    __shared__ int s[1024];
    const int tid = threadIdx.x;
    const int idx = blockIdx.x * 1024 + tid;
    int v = (idx < n) ? counts[idx] : 0;
    s[tid] = v;
    __syncthreads();
    for (int off = 1; off < 1024; off <<= 1) {
        int t = (tid >= off) ? s[tid - off] : 0;
        __syncthreads();
        s[tid] += t;
        __syncthreads();
    }
    if (idx < n) local[idx] = s[tid] - v;
    if (tid == 1023) blocksums[blockIdx.x] = s[1023];
}

__global__ __launch_bounds__(1024) void scan_sums(int* __restrict__ blocksums, int nb) {
    __shared__ int s[1024];
    const int tid = threadIdx.x;
    int v = (tid < nb) ? blocksums[tid] : 0;
    s[tid] = v;
    __syncthreads();
    for (int off = 1; off < 1024; off <<= 1) {
        int t = (tid >= off) ? s[tid - off] : 0;
        __syncthreads();
        s[tid] += t;
        __syncthreads();
    }
    if (tid < nb) blocksums[tid] = s[tid] - v;
}

__global__ __launch_bounds__(256) void scan_finalize(int* __restrict__ offsets,
                                                     int* __restrict__ cursor,
                                                     const int* __restrict__ blockoffs,
                                                     int n, int total) {
    int idx = blockIdx.x * blockDim.x + threadIdx.x;
    if (idx < n) {
        int o = offsets[idx] + blockoffs[idx >> 10];
        offsets[idx] = o;
        cursor[idx] = o;
    }
    if (idx == 0) offsets[n] = total;
}

// Partitioned ticket-scatter. Payload: (fp16 w << 16) | u16 src.
__global__ __launch_bounds__(256) void sort_edges_part(const int* __restrict__ src,
                                                       const int* __restrict__ dst,
                                                       const float* __restrict__ w,
                                                       int* __restrict__ cursor,
                                                       unsigned* __restrict__ pk,
                                                       int E, int span, int M) {
    const int g = blockIdx.x & 7;
    const int rank = blockIdx.x >> 3;
    const int nrank = gridDim.x >> 3;
    const int lo = g * span;
    const int hi = min(lo + span, M);
    for (int e = rank * blockDim.x + threadIdx.x; e < E; e += nrank * blockDim.x) {
        int d = dst[e];
        if (d >= lo && d < hi) {
            int pos = atomicAdd(&cursor[d], 1);
            pk[pos] = ((unsigned)f2h(w[e]) << 16) | (unsigned)src[e];
        }
    }
}

// ---------------- Gather conv layer-1 (bf16 h -> relu -> bf16 z) ----------------
__global__ __launch_bounds__(256) void gather_conv_pk(const unsigned short* __restrict__ h,
                                                      const int* __restrict__ offsets,
                                                      const unsigned* __restrict__ pk,
                                                      unsigned short* __restrict__ z, int N) {
    const int lane = threadIdx.x & 63;
    const int wid = threadIdx.x >> 6;
    const int node = blockIdx.x * 4 + wid;
    if (node >= N) return;
    const int s0 = offsets[node];
    const int s1 = offsets[node + 1];
    float a0 = 0.f, a1 = 0.f, a2 = 0.f, a3 = 0.f;
    int i = s0;
    for (; i + 4 <= s1; i += 4) {
        unsigned qA = pk[i], qB = pk[i + 1], qC = pk[i + 2], qD = pk[i + 3];
        float wA = h2f(qA >> 16), wB = h2f(qB >> 16), wC = h2f(qC >> 16), wD = h2f(qD >> 16);
        ushort4 vA = ((const ushort4*)(h + (size_t)(qA & 0xffffu) * NHID))[lane];
        ushort4 vB = ((const ushort4*)(h + (size_t)(qB & 0xffffu) * NHID))[lane];
        ushort4 vC = ((const ushort4*)(h + (size_t)(qC & 0xffffu) * NHID))[lane];
        ushort4 vD = ((const ushort4*)(h + (size_t)(qD & 0xffffu) * NHID))[lane];
        a0 += wA * b2f(vA.x) + wB * b2f(vB.x) + wC * b2f(vC.x) + wD * b2f(vD.x);
        a1 += wA * b2f(vA.y) + wB * b2f(vB.y) + wC * b2f(vC.y) + wD * b2f(vD.y);
        a2 += wA * b2f(vA.z) + wB * b2f(vB.z) + wC * b2f(vC.z) + wD * b2f(vD.z);
        a3 += wA * b2f(vA.w) + wB * b2f(vB.w) + wC * b2f(vC.w) + wD * b2f(vD.w);
    }
    for (; i < s1; ++i) {
        unsigned q = pk[i];
        float ww = h2f(q >> 16);
        ushort4 v = ((const ushort4*)(h + (size_t)(q & 0xffffu) * NHID))[lane];
        a0 += ww * b2f(v.x);
        a1 += ww * b2f(v.y);
        a2 += ww * b2f(v.z);
        a3 += ww * b2f(v.w);
    }
    a0 = fmaxf(a0, 0.f); a1 = fmaxf(a1, 0.f);
    a2 = fmaxf(a2, 0.f); a3 = fmaxf(a3, 0.f);
    ushort4 o;
    o.x = f2b(a0); o.y = f2b(a1); o.z = f2b(a2); o.w = f2b(a3);
    ((ushort4*)(z + (size_t)node * NHID))[lane] = o;
}

// ---------------- Gather conv layer-2 fused with Wlin projection ----------------
__global__ __launch_bounds__(256) void gather_wlin_pk(const unsigned short* __restrict__ h,
                                                      const int* __restrict__ offsets,
                                                      const unsigned* __restrict__ pk,
                                                      const float* __restrict__ Wlin,
                                                      float2* __restrict__ za,
                                                      float2* __restrict__ zb, int N) {
    const int lane = threadIdx.x & 63;
    const int wid = threadIdx.x >> 6;
    const int node = blockIdx.x * 4 + wid;
    if (node >= N) return;

    float wt[8], wbm[8];
#pragma unroll
    for (int i = 0; i < 8; ++i) {
        wt[i]  = Wlin[(lane * 4) * 2 + i];
        wbm[i] = Wlin[(NHID + lane * 4) * 2 + i];
    }

    const int s0 = offsets[node];
    const int s1 = offsets[node + 1];
    float a0 = 0.f, a1 = 0.f, a2 = 0.f, a3 = 0.f;
    int i = s0;
    for (; i + 4 <= s1; i += 4) {
        unsigned qA = pk[i], qB = pk[i + 1], qC = pk[i + 2], qD = pk[i + 3];
        float wA = h2f(qA >> 16), wB = h2f(qB >> 16), wC = h2f(qC >> 16), wD = h2f(qD >> 16);
        ushort4 vA = ((const ushort4*)(h + (size_t)(qA & 0xffffu) * NHID))[lane];
        ushort4 vB = ((const ushort4*)(h + (size_t)(qB & 0xffffu) * NHID))[lane];
        ushort4 vC = ((const ushort4*)(h + (size_t)(qC & 0xffffu) * NHID))[lane];
        ushort4 vD = ((const ushort4*)(h + (size_t)(qD & 0xffffu) * NHID))[lane];
        a0 += wA * b2f(vA.x) + wB * b2f(vB.x) + wC * b2f(vC.x) + wD * b2f(vD.x);
        a1 += wA * b2f(vA.y) + wB * b2f(vB.y) + wC * b2f(vC.y) + wD * b2f(vD.y);
        a2 += wA * b2f(vA.z) + wB * b2f(vB.z) + wC * b2f(vC.z) + wD * b2f(vD.z);
        a3 += wA * b2f(vA.w) + wB * b2f(vB.w) + wC * b2f(vC.w) + wD * b2f(vD.w);
    }
    for (; i < s1; ++i) {
        unsigned q = pk[i];
        float ww = h2f(q >> 16);
        ushort4 v = ((const ushort4*)(h + (size_t)(q & 0xffffu) * NHID))[lane];
        a0 += ww * b2f(v.x);
        a1 += ww * b2f(v.y);
        a2 += ww * b2f(v.z);
        a3 += ww * b2f(v.w);
    }

    float pa0 = a0 * wt[0] + a1 * wt[2] + a2 * wt[4] + a3 * wt[6];
    float pa1 = a0 * wt[1] + a1 * wt[3] + a2 * wt[5] + a3 * wt[7];
    float pb0 = a0 * wbm[0] + a1 * wbm[2] + a2 * wbm[4] + a3 * wbm[6];
    float pb1 = a0 * wbm[1] + a1 * wbm[3] + a2 * wbm[5] + a3 * wbm[7];
#pragma unroll
    for (int off = 32; off > 0; off >>= 1) {
        pa0 += __shfl_down(pa0, off);
        pa1 += __shfl_down(pa1, off);
        pb0 += __shfl_down(pb0, off);
        pb1 += __shfl_down(pb1, off);
    }
    if (lane == 0) {
        za[node] = {pa0, pa1};
        zb[node] = {pb0, pb1};
    }
}

// ---------------- Decode: out[p] = za[ps[p]] + zb[pd[p]] ----------------
__global__ __launch_bounds__(256) void decode_pairs(const float2* __restrict__ za,
                                                    const float2* __restrict__ zb,
                                                    const int* __restrict__ ps,
                                                    const int* __restrict__ pd,
                                                    float2* __restrict__ out, int P) {
    int p = blockIdx.x * blockDim.x + threadIdx.x;
    if (p < P) {
        float2 va = za[ps[p]];
        float2 vb = zb[pd[p]];
        out[p] = {va.x + vb.x, va.y + vb.y};
    }
}

// ================= fp32 fallback path (ws too small or M > 65535) =================
template <bool RELU>
__global__ __launch_bounds__(256) void gemm_tiled(const float* __restrict__ A,
                                                  const float* __restrict__ B,
                                                  float* __restrict__ C,
                                                  int M, int N, int K) {
    __shared__ float As[16][65];
    __shared__ float Bs[16][64];
    const int block_row = blockIdx.x * 64;
    const int block_col = blockIdx.y * 64;
    const int tid = threadIdx.x;
    const int tx = tid & 15;
    const int ty = tid >> 4;
    float c[4][4] = {};
    for (int k0 = 0; k0 < K; k0 += 16) {
#pragma unroll
        for (int i = 0; i < 4; ++i) {
            int idx = tid + i * 256;
            int kk = idx & 15;
            int m = idx >> 4;
            int row = block_row + m;
            float v = 0.f;
            if (row < M) v = A[(long)row * K + k0 + kk];
            if (RELU) v = fmaxf(v, 0.f);
            As[kk][m] = v;
        }
#pragma unroll
        for (int i = 0; i < 4; ++i) {
            int idx = tid + i * 256;
            int n = idx & 63;
            int kk = idx >> 6;
            Bs[kk][n] = B[(long)(k0 + kk) * N + block_col + n];
        }
        __syncthreads();
#pragma unroll
        for (int kk = 0; kk < 16; ++kk) {
            float a[4], b[4];
#pragma unroll
            for (int i = 0; i < 4; ++i) a[i] = As[kk][ty * 4 + i];
#pragma unroll
            for (int j = 0; j < 4; ++j) b[j] = Bs[kk][tx * 4 + j];
#pragma unroll
            for (int i = 0; i < 4; ++i)
#pragma unroll
                for (int j = 0; j < 4; ++j) c[i][j] += a[i] * b[j];
        }
        __syncthreads();
    }
#pragma unroll
    for (int i = 0; i < 4; ++i) {
        int row = block_row + ty * 4 + i;
        if (row < M) {
            float* cp = C + (long)row * N + block_col + tx * 4;
#pragma unroll
            for (int j = 0; j < 4; ++j) cp[j] = c[i][j];
        }
    }
}

__global__ __launch_bounds__(256) void scatter_conv(const float* __restrict__ h,
                                                    const int* __restrict__ src,
                                                    const int* __restrict__ dst,
                                                    const float* __restrict__ w,
                                                    float* __restrict__ z, int E) {
    const int lane = threadIdx.x & 63;
    const int wid = threadIdx.x >> 6;
    const int nwaves = (gridDim.x * blockDim.x) >> 6;
    for (int e = blockIdx.x * 4 + wid; e < E; e += nwaves) {
        int s = src[e];
        int d = dst[e];
        float ww = w[e];
        float4 v = ((const float4*)(h + (long)s * NHID))[lane];
        float* zp = z + (long)d * NHID + lane * 4;
        atomicAdd(zp + 0, ww * v.x);
        atomicAdd(zp + 1, ww * v.y);
        atomicAdd(zp + 2, ww * v.z);
        atomicAdd(zp + 3, ww * v.w);
    }
}

__global__ __launch_bounds__(256) void decode_f(const float* __restrict__ z,
                                                const int* __restrict__ ps,
                                                const int* __restrict__ pd,
                                                const float* __restrict__ Wlin,
                                                float* __restrict__ out, int P) {
    const int lane = threadIdx.x & 63;
    const int wid = threadIdx.x >> 6;
    const int nwaves = (gridDim.x * blockDim.x) >> 6;
    float wa[8], wb[8];
#pragma unroll
    for (int i = 0; i < 8; ++i) {
        wa[i] = Wlin[(lane * 4) * 2 + i];
        wb[i] = Wlin[(NHID + lane * 4) * 2 + i];
    }
    for (int p = blockIdx.x * 4 + wid; p < P; p += nwaves) {
        int a = ps[p];
        int b = pd[p];
        float4 va = ((const float4*)(z + (long)a * NHID))[lane];
        float4 vb = ((const float4*)(z + (long)b * NHID))[lane];
        float acc0 = va.x * wa[0] + va.y * wa[2] + va.z * wa[4] + va.w * wa[6]
                   + vb.x * wb[0] + vb.y * wb[2] + vb.z * wb[4] + vb.w * wb[6];
        float acc1 = va.x * wa[1] + va.y * wa[3] + va.z * wa[5] + va.w * wa[7]
                   + vb.x * wb[1] + vb.y * wb[3] + vb.z * wb[5] + vb.w * wb[7];
#pragma unroll
        for (int off = 32; off > 0; off >>= 1) {
            acc0 += __shfl_down(acc0, off);
            acc1 += __shfl_down(acc1, off);
        }
        if (lane == 0) {
            out[(long)p * 2 + 0] = acc0;
            out[(long)p * 2 + 1] = acc1;
        }
    }
}

extern "C" void kernel_launch(void* const* d_in, const int* in_sizes, int n_in,
                              void* d_out, int out_size, void* d_ws, size_t ws_size,
                              hipStream_t stream) {
    (void)n_in; (void)out_size;
    const float* x    = (const float*)d_in[0];   // [M, 512]
    const int*   ei   = (const int*)d_in[1];     // [2, E]
    const float* ew   = (const float*)d_in[2];   // [E]
    const int*   pei  = (const int*)d_in[3];     // [2, P]
    const float* W1   = (const float*)d_in[4];   // [512, 256]
    const float* W2   = (const float*)d_in[5];   // [256, 256]
    const float* Wlin = (const float*)d_in[6];   // [512, 2]
    float* out = (float*)d_out;                  // [P, 2]

    const int E = in_sizes[2];
    const int P = in_sizes[3] / 2;
    const int M = in_sizes[0] / NFEAT;

    dim3 blk(256);
    const int* src = ei;
    const int* dst = ei + E;

    // workspace layout (bf16 path)
    unsigned short* hA = (unsigned short*)d_ws;               // [M,256] bf16
    unsigned short* hB = hA + (size_t)M * NHID;               // [M,256] bf16
    int* offsets = (int*)(hB + (size_t)M * NHID);             // [M+1]
    int* cursor  = offsets + (M + 1);                          // [M]
    unsigned* pk = (unsigned*)(cursor + M);                    // [E] packed (f16 w | u16 src)
    int* blocksums = (int*)(pk + E);                           // [1024]
    float2* za = (float2*)(blocksums + 1024);                  // [M]
    float2* zb = za + M;                                       // [M]
    const size_t need = 2 * (size_t)M * NHID * 2 + ((size_t)2 * M + 1) * 4
                      + (size_t)E * 4 + 1024 * 4 + (size_t)M * 2 * 8;

    if (ws_size >= need && M <= 65535) {
        unsigned short* W1bT = (unsigned short*)d_out;        // [256,512] bf16 (256 KB)
        unsigned short* W2bT = W1bT + (size_t)NHID * NFEAT;   // [256,256] bf16 (128 KB)

        transposeW2<<<(NFEAT * NHID + NHID * NHID + 255) / 256, blk, 0, stream>>>(W1, W2, W1bT, W2bT);

        // ---- CSR build (XCD-range-partitioned hist + sort) ----
        const int span = (M + 7) / 8;
        const int nb = (M + 1023) / 1024;
        hipMemsetAsync(cursor, 0, (size_t)M * sizeof(int), stream);
        hist_part<<<2048, blk, 0, stream>>>(dst, cursor, E, span, M);
        scan_local<<<nb, 1024, 0, stream>>>(cursor, offsets, blocksums, M);
        scan_sums<<<1, 1024, 0, stream>>>(blocksums, nb);
        scan_finalize<<<(M + 255) / 256, blk, 0, stream>>>(offsets, cursor, blocksums, M, E);
        sort_edges_part<<<2048, blk, 0, stream>>>(src, dst, ew, cursor, pk, E, span, M);

        // ---- Layer 1: hA = x(bf16-converted) @ W1 ----
        dim3 g1((M + BM - 1) / BM, NHID / BN);
        gemm_mfma<float><<<g1, blk, 0, stream>>>(x, W1bT, hA, M, NHID, NFEAT);
        gather_conv_pk<<<(M + 3) / 4, blk, 0, stream>>>(hA, offsets, pk, hB, M);
        // ---- Layer 2 + fused Wlin projection ----
        gemm_mfma<unsigned short><<<g1, blk, 0, stream>>>(hB, W2bT, hA, M, NHID, NHID);
        gather_wlin_pk<<<(M + 3) / 4, blk, 0, stream>>>(hA, offsets, pk, Wlin, za, zb, M);
        // ---- Decode ----
        decode_pairs<<<(P + 255) / 256, blk, 0, stream>>>(za, zb, pei, pei + P, (float2*)out, P);
    } else {
        // fp32 atomic fallback
        float* bufA = (float*)d_ws;
        float* bufB = bufA + (size_t)M * NHID;
        const size_t zbytes = (size_t)M * NHID * sizeof(float);
        dim3 gemm_grid((M + 63) / 64, NHID / 64);
        gemm_tiled<false><<<gemm_grid, blk, 0, stream>>>(x, W1, bufA, M, NHID, NFEAT);
        hipMemsetAsync(bufB, 0, zbytes, stream);
        scatter_conv<<<2048, blk, 0, stream>>>(bufA, src, dst, ew, bufB, E);
        gemm_tiled<true><<<gemm_grid, blk, 0, stream>>>(bufB, W2, bufA, M, NHID, NHID);
        hipMemsetAsync(bufB, 0, zbytes, stream);
        scatter_conv<<<2048, blk, 0, stream>>>(bufA, src, dst, ew, bufB, E);
        decode_f<<<(P + 3) / 4, blk, 0, stream>>>(bufB, pei, pei + P, Wlin, out, P);
    }
}

// Round 8
// 262.306 us; speedup vs baseline: 21.9140x; 1.0486x over previous
//
#include <hip/hip_runtime.h>

#define NHID 256
#define NFEAT 512
#define BM 64
#define BN 128
#define BKE 32

using short8  = __attribute__((ext_vector_type(8))) short;
using float8  = __attribute__((ext_vector_type(8))) float;
using f32x4   = __attribute__((ext_vector_type(4))) float;

__device__ __forceinline__ float b2f(unsigned short u) {
    union { float f; unsigned v; } c;
    c.v = ((unsigned)u) << 16;
    return c.f;
}
__device__ __forceinline__ unsigned short f2b(float f) {
    union { float f; unsigned u; } c;
    c.f = f;
    unsigned r = c.u + 0x7fffu + ((c.u >> 16) & 1u);  // RNE
    return (unsigned short)(r >> 16);
}
__device__ __forceinline__ unsigned short f2h(float f) {
    union { _Float16 h; unsigned short u; } c;
    c.h = (_Float16)f;
    return c.u;
}
__device__ __forceinline__ float h2f(unsigned short u) {
    union { _Float16 h; unsigned short u; } c;
    c.u = u;
    return (float)c.h;
}

// async global->LDS, 16 B per lane; lds base must be wave-uniform, gsrc per-lane.
__device__ __forceinline__ void gload16(const void* gsrc, void* lds) {
    __builtin_amdgcn_global_load_lds((const __attribute__((address_space(1))) unsigned int*)gsrc,
                                     (__attribute__((address_space(3))) unsigned int*)lds,
                                     16, 0, 0);
}

// ---------------- W transposes + cursor zero, one launch ----------------
__global__ __launch_bounds__(256) void transposeW2z(const float* __restrict__ W1,
                                                    const float* __restrict__ W2,
                                                    unsigned short* __restrict__ W1bT,
                                                    unsigned short* __restrict__ W2bT,
                                                    int* __restrict__ cursor, int M) {
    int i = blockIdx.x * blockDim.x + threadIdx.x;
    const int t1 = NFEAT * NHID;
    const int t2 = NHID * NHID;
    if (i < t1) {
        int k = i >> 8, n = i & 255;
        W1bT[(size_t)n * NFEAT + k] = f2b(W1[i]);
    } else if (i < t1 + t2) {
        int j = i - t1;
        int k = j >> 8, n = j & 255;
        W2bT[(size_t)n * NHID + k] = f2b(W2[j]);
    } else {
        int j = i - t1 - t2;
        if (j < M) cursor[j] = 0;
    }
}

// ---------------- GEMM1: C[M,256] = cvt_bf16(A_f32[M,512]) @ BT[256,512]^T ----------------
// 64x128 tile, 4 waves, acc[2][4]/wave. A reg-staged+converted (padded LDS),
// B staged via global_load_lds (linear LDS). Double-buffered, 1 barrier/K-step.
__global__ __launch_bounds__(256) void gemm1_mfma(const float* __restrict__ A,
                                                  const unsigned short* __restrict__ BT,
                                                  unsigned short* __restrict__ C, int M) {
    const int K = NFEAT;
    constexpr int LDA = 40;   // padded bf16 row (80 B) -> 2-way conflicts (free)
    __shared__ unsigned short As[2][BM * LDA];
    __shared__ unsigned short Bs[2][BN * 32];   // linear [row][32]
    const int tid = threadIdx.x;
    const int lane = tid & 63;
    const int wid = tid >> 6;
    const int wr = wid >> 1, wc = wid & 1;
    const int bcol = blockIdx.x * BN;
    const int brow = blockIdx.y * BM;

    // A staging: thread covers row tid>>2, k chunk (tid&3)*8
    const int arow = tid >> 2;
    const int akp = (tid & 3) * 8;
    int agrow = brow + arow; if (agrow >= M) agrow = M - 1;
    const float* aptr = A + (size_t)agrow * K + akp;

    // B staging via gload: 2 calls/wave, 16 rows each (row = base + lane>>2, inner (lane&3)*8 elems)
    const unsigned short* bgp0 = BT + (size_t)(bcol + wid * 32 + (lane >> 2)) * K + (lane & 3) * 8;
    const unsigned short* bgp1 = BT + (size_t)(bcol + wid * 32 + 16 + (lane >> 2)) * K + (lane & 3) * 8;
    const int bw = wid * 32 * 32;   // wave's LDS base offset (elems)

    const int lrow = lane & 15;
    const int lk = (lane >> 4) * 8;

    f32x4 acc[2][4] = {};
    const int nt = K / BKE;

    // prologue: stage tile 0
    {
        gload16(bgp0, &Bs[0][bw]);
        gload16(bgp1, &Bs[0][bw + 16 * 32]);
        float8 t0 = *(const float8*)aptr;
        short8 v;
#pragma unroll
        for (int j = 0; j < 8; ++j) v[j] = (short)f2b(t0[j]);
        *(short8*)(&As[0][arow * LDA + akp]) = v;
    }
    __syncthreads();

    int p = 0;
    for (int t = 0; t < nt; ++t) {
        float8 pa = {};
        if (t + 1 < nt) {
            const int k0 = (t + 1) * BKE;
            unsigned short* bd = &Bs[p ^ 1][bw];
            gload16(bgp0 + k0, bd);
            gload16(bgp1 + k0, bd + 16 * 32);
            pa = *(const float8*)(aptr + k0);
        }
        const unsigned short* Asp = &As[p][0];
        const unsigned short* Bsp = &Bs[p][0];
        short8 a[2], b[4];
#pragma unroll
        for (int m = 0; m < 2; ++m)
            a[m] = *(const short8*)(Asp + (wr * 32 + m * 16 + lrow) * LDA + lk);
#pragma unroll
        for (int n = 0; n < 4; ++n)
            b[n] = *(const short8*)(Bsp + (wc * 64 + n * 16 + lrow) * 32 + lk);
#pragma unroll
        for (int m = 0; m < 2; ++m)
#pragma unroll
            for (int n = 0; n < 4; ++n)
                acc[m][n] = __builtin_amdgcn_mfma_f32_16x16x32_bf16(a[m], b[n], acc[m][n], 0, 0, 0);
        if (t + 1 < nt) {
            short8 v;
#pragma unroll
            for (int j = 0; j < 8; ++j) v[j] = (short)f2b(pa[j]);
            *(short8*)(&As[p ^ 1][arow * LDA + akp]) = v;
        }
        __syncthreads();
        p ^= 1;
    }

#pragma unroll
    for (int m = 0; m < 2; ++m)
#pragma unroll
        for (int r = 0; r < 4; ++r) {
            int row = brow + wr * 32 + m * 16 + (lane >> 4) * 4 + r;
            if (row < M) {
#pragma unroll
                for (int n = 0; n < 4; ++n) {
                    int col = bcol + wc * 64 + n * 16 + (lane & 15);
                    C[(size_t)row * NHID + col] = f2b(acc[m][n][r]);
                }
            }
        }
}

// ---------------- GEMM2: C[M,256] = A_bf16[M,256] @ BT[256,256]^T ----------------
// Both operands staged via global_load_lds (linear LDS).
__global__ __launch_bounds__(256) void gemm2_mfma(const unsigned short* __restrict__ A,
                                                  const unsigned short* __restrict__ BT,
                                                  unsigned short* __restrict__ C, int M) {
    const int K = NHID;
    __shared__ unsigned short As[2][BM * 32];
    __shared__ unsigned short Bs[2][BN * 32];
    const int tid = threadIdx.x;
    const int lane = tid & 63;
    const int wid = tid >> 6;
    const int wr = wid >> 1, wc = wid & 1;
    const int bcol = blockIdx.x * BN;
    const int brow = blockIdx.y * BM;

    // A: 1 call/wave (16 rows)
    int ar = brow + wid * 16 + (lane >> 2); if (ar >= M) ar = M - 1;
    const unsigned short* agp = A + (size_t)ar * K + (lane & 3) * 8;
    const int aw = wid * 16 * 32;
    // B: 2 calls/wave
    const unsigned short* bgp0 = BT + (size_t)(bcol + wid * 32 + (lane >> 2)) * K + (lane & 3) * 8;
    const unsigned short* bgp1 = BT + (size_t)(bcol + wid * 32 + 16 + (lane >> 2)) * K + (lane & 3) * 8;
    const int bw = wid * 32 * 32;

    const int lrow = lane & 15;
    const int lk = (lane >> 4) * 8;

    f32x4 acc[2][4] = {};
    const int nt = K / BKE;

    gload16(agp, &As[0][aw]);
    gload16(bgp0, &Bs[0][bw]);
    gload16(bgp1, &Bs[0][bw + 16 * 32]);
    __syncthreads();

    int p = 0;
    for (int t = 0; t < nt; ++t) {
        if (t + 1 < nt) {
            const int k0 = (t + 1) * BKE;
            gload16(agp + k0, &As[p ^ 1][aw]);
            unsigned short* bd = &Bs[p ^ 1][bw];
            gload16(bgp0 + k0, bd);
            gload16(bgp1 + k0, bd + 16 * 32);
        }
        const unsigned short* Asp = &As[p][0];
        const unsigned short* Bsp = &Bs[p][0];
        short8 a[2], b[4];
#pragma unroll
        for (int m = 0; m < 2; ++m)
            a[m] = *(const short8*)(Asp + (wr * 32 + m * 16 + lrow) * 32 + lk);
#pragma unroll
        for (int n = 0; n < 4; ++n)
            b[n] = *(const short8*)(Bsp + (wc * 64 + n * 16 + lrow) * 32 + lk);
#pragma unroll
        for (int m = 0; m < 2; ++m)
#pragma unroll
            for (int n = 0; n < 4; ++n)
                acc[m][n] = __builtin_amdgcn_mfma_f32_16x16x32_bf16(a[m], b[n], acc[m][n], 0, 0, 0);
        __syncthreads();
        p ^= 1;
    }

#pragma unroll
    for (int m = 0; m < 2; ++m)
#pragma unroll
        for (int r = 0; r < 4; ++r) {
            int row = brow + wr * 32 + m * 16 + (lane >> 4) * 4 + r;
            if (row < M) {
#pragma unroll
                for (int n = 0; n < 4; ++n) {
                    int col = bcol + wc * 64 + n * 16 + (lane & 15);
                    C[(size_t)row * NHID + col] = f2b(acc[m][n][r]);
                }
            }
        }
}

// ---------------- CSR build, XCD-range-partitioned ----------------
__global__ __launch_bounds__(256) void hist_part(const int* __restrict__ dst,
                                                 int* __restrict__ counts,
                                                 int E, int span, int M) {
    const int g = blockIdx.x & 7;
    const int rank = blockIdx.x >> 3;
    const int nrank = gridDim.x >> 3;
    const int lo = g * span;
    const int hi = min(lo + span, M);
    for (int e = rank * blockDim.x + threadIdx.x; e < E; e += nrank * blockDim.x) {
        int d = dst[e];
        if (d >= lo && d < hi) atomicAdd(&counts[d], 1);
    }
}

__global__ __launch_bounds__(1024) void scan_local(const int* __restrict__ counts,
                                                   int* __restrict__ local,
                                                   int* __restrict__ blocksums, int n) {
    __shared__ int s[1024];
    const int tid = threadIdx.x;
    const int idx = blockIdx.x * 1024 + tid;
    int v = (idx < n) ? counts[idx] : 0;
    s[tid] = v;
    __syncthreads();
    for (int off = 1; off < 1024; off <<= 1) {
        int t = (tid >= off) ? s[tid - off] : 0;
        __syncthreads();
        s[tid] += t;
        __syncthreads();
    }
    if (idx < n) local[idx] = s[tid] - v;
    if (tid == 1023) blocksums[blockIdx.x] = s[1023];
}

__global__ __launch_bounds__(1024) void scan_sums(int* __restrict__ blocksums, int nb) {
    __shared__ int s[1024];
    const int tid = threadIdx.x;
    int v = (tid < nb) ? blocksums[tid] : 0;
    s[tid] = v;
    __syncthreads();
    for (int off = 1; off < 1024; off <<= 1) {
        int t = (tid >= off) ? s[tid - off] : 0;
        __syncthreads();
        s[tid] += t;
        __syncthreads();
    }
    if (tid < nb) blocksums[tid] = s[tid] - v;
}

__global__ __launch_bounds__(256) void scan_finalize(int* __restrict__ offsets,
                                                     int* __restrict__ cursor,
                                                     const int* __restrict__ blockoffs,
                                                     int n, int total) {
    int idx = blockIdx.x * blockDim.x + threadIdx.x;
    if (idx < n) {
        int o = offsets[idx] + blockoffs[idx >> 10];
        offsets[idx] = o;
        cursor[idx] = o;
    }
    if (idx == 0) offsets[n] = total;
}

__global__ __launch_bounds__(256) void sort_edges_part(const int* __restrict__ src,
                                                       const int* __restrict__ dst,
                                                       const float* __restrict__ w,
                                                       int* __restrict__ cursor,
                                                       unsigned* __restrict__ pk,
                                                       int E, int span, int M) {
    const int g = blockIdx.x & 7;
    const int rank = blockIdx.x >> 3;
    const int nrank = gridDim.x >> 3;
    const int lo = g * span;
    const int hi = min(lo + span, M);
    for (int e = rank * blockDim.x + threadIdx.x; e < E; e += nrank * blockDim.x) {
        int d = dst[e];
        if (d >= lo && d < hi) {
            int pos = atomicAdd(&cursor[d], 1);
            pk[pos] = ((unsigned)f2h(w[e]) << 16) | (unsigned)src[e];
        }
    }
}

// ---------------- Gather conv layer-1 (bf16 h -> relu -> bf16 z) ----------------
__global__ __launch_bounds__(256) void gather_conv_pk(const unsigned short* __restrict__ h,
                                                      const int* __restrict__ offsets,
                                                      const unsigned* __restrict__ pk,
                                                      unsigned short* __restrict__ z, int N) {
    const int lane = threadIdx.x & 63;
    const int wid = threadIdx.x >> 6;
    const int node = blockIdx.x * 4 + wid;
    if (node >= N) return;
    const int s0 = offsets[node];
    const int s1 = offsets[node + 1];
    float a0 = 0.f, a1 = 0.f, a2 = 0.f, a3 = 0.f;
    int i = s0;
    for (; i + 4 <= s1; i += 4) {
        unsigned qA = pk[i], qB = pk[i + 1], qC = pk[i + 2], qD = pk[i + 3];
        float wA = h2f(qA >> 16), wB = h2f(qB >> 16), wC = h2f(qC >> 16), wD = h2f(qD >> 16);
        ushort4 vA = ((const ushort4*)(h + (size_t)(qA & 0xffffu) * NHID))[lane];
        ushort4 vB = ((const ushort4*)(h + (size_t)(qB & 0xffffu) * NHID))[lane];
        ushort4 vC = ((const ushort4*)(h + (size_t)(qC & 0xffffu) * NHID))[lane];
        ushort4 vD = ((const ushort4*)(h + (size_t)(qD & 0xffffu) * NHID))[lane];
        a0 += wA * b2f(vA.x) + wB * b2f(vB.x) + wC * b2f(vC.x) + wD * b2f(vD.x);
        a1 += wA * b2f(vA.y) + wB * b2f(vB.y) + wC * b2f(vC.y) + wD * b2f(vD.y);
        a2 += wA * b2f(vA.z) + wB * b2f(vB.z) + wC * b2f(vC.z) + wD * b2f(vD.z);
        a3 += wA * b2f(vA.w) + wB * b2f(vB.w) + wC * b2f(vC.w) + wD * b2f(vD.w);
    }
    for (; i < s1; ++i) {
        unsigned q = pk[i];
        float ww = h2f(q >> 16);
        ushort4 v = ((const ushort4*)(h + (size_t)(q & 0xffffu) * NHID))[lane];
        a0 += ww * b2f(v.x);
        a1 += ww * b2f(v.y);
        a2 += ww * b2f(v.z);
        a3 += ww * b2f(v.w);
    }
    a0 = fmaxf(a0, 0.f); a1 = fmaxf(a1, 0.f);
    a2 = fmaxf(a2, 0.f); a3 = fmaxf(a3, 0.f);
    ushort4 o;
    o.x = f2b(a0); o.y = f2b(a1); o.z = f2b(a2); o.w = f2b(a3);
    ((ushort4*)(z + (size_t)node * NHID))[lane] = o;
}

// ---------------- Gather conv layer-2 fused with Wlin projection ----------------
__global__ __launch_bounds__(256) void gather_wlin_pk(const unsigned short* __restrict__ h,
                                                      const int* __restrict__ offsets,
                                                      const unsigned* __restrict__ pk,
                                                      const float* __restrict__ Wlin,
                                                      float2* __restrict__ za,
                                                      float2* __restrict__ zb, int N) {
    const int lane = threadIdx.x & 63;
    const int wid = threadIdx.x >> 6;
    const int node = blockIdx.x * 4 + wid;
    if (node >= N) return;

    float wt[8], wbm[8];
#pragma unroll
    for (int i = 0; i < 8; ++i) {
        wt[i]  = Wlin[(lane * 4) * 2 + i];
        wbm[i] = Wlin[(NHID + lane * 4) * 2 + i];
    }

    const int s0 = offsets[node];
    const int s1 = offsets[node + 1];
    float a0 = 0.f, a1 = 0.f, a2 = 0.f, a3 = 0.f;
    int i = s0;
    for (; i + 4 <= s1; i += 4) {
        unsigned qA = pk[i], qB = pk[i + 1], qC = pk[i + 2], qD = pk[i + 3];
        float wA = h2f(qA >> 16), wB = h2f(qB >> 16), wC = h2f(qC >> 16), wD = h2f(qD >> 16);
        ushort4 vA = ((const ushort4*)(h + (size_t)(qA & 0xffffu) * NHID))[lane];
        ushort4 vB = ((const ushort4*)(h + (size_t)(qB & 0xffffu) * NHID))[lane];
        ushort4 vC = ((const ushort4*)(h + (size_t)(qC & 0xffffu) * NHID))[lane];
        ushort4 vD = ((const ushort4*)(h + (size_t)(qD & 0xffffu) * NHID))[lane];
        a0 += wA * b2f(vA.x) + wB * b2f(vB.x) + wC * b2f(vC.x) + wD * b2f(vD.x);
        a1 += wA * b2f(vA.y) + wB * b2f(vB.y) + wC * b2f(vC.y) + wD * b2f(vD.y);
        a2 += wA * b2f(vA.z) + wB * b2f(vB.z) + wC * b2f(vC.z) + wD * b2f(vD.z);
        a3 += wA * b2f(vA.w) + wB * b2f(vB.w) + wC * b2f(vC.w) + wD * b2f(vD.w);
    }
    for (; i < s1; ++i) {
        unsigned q = pk[i];
        float ww = h2f(q >> 16);
        ushort4 v = ((const ushort4*)(h + (size_t)(q & 0xffffu) * NHID))[lane];
        a0 += ww * b2f(v.x);
        a1 += ww * b2f(v.y);
        a2 += ww * b2f(v.z);
        a3 += ww * b2f(v.w);
    }

    float pa0 = a0 * wt[0] + a1 * wt[2] + a2 * wt[4] + a3 * wt[6];
    float pa1 = a0 * wt[1] + a1 * wt[3] + a2 * wt[5] + a3 * wt[7];
    float pb0 = a0 * wbm[0] + a1 * wbm[2] + a2 * wbm[4] + a3 * wbm[6];
    float pb1 = a0 * wbm[1] + a1 * wbm[3] + a2 * wbm[5] + a3 * wbm[7];
#pragma unroll
    for (int off = 32; off > 0; off >>= 1) {
        pa0 += __shfl_down(pa0, off);
        pa1 += __shfl_down(pa1, off);
        pb0 += __shfl_down(pb0, off);
        pb1 += __shfl_down(pb1, off);
    }
    if (lane == 0) {
        za[node] = {pa0, pa1};
        zb[node] = {pb0, pb1};
    }
}

// ---------------- Decode: out[p] = za[ps[p]] + zb[pd[p]] ----------------
__global__ __launch_bounds__(256) void decode_pairs(const float2* __restrict__ za,
                                                    const float2* __restrict__ zb,
                                                    const int* __restrict__ ps,
                                                    const int* __restrict__ pd,
                                                    float2* __restrict__ out, int P) {
    int p = blockIdx.x * blockDim.x + threadIdx.x;
    if (p < P) {
        float2 va = za[ps[p]];
        float2 vb = zb[pd[p]];
        out[p] = {va.x + vb.x, va.y + vb.y};
    }
}

// ================= fp32 fallback path (ws too small or M > 65535) =================
template <bool RELU>
__global__ __launch_bounds__(256) void gemm_tiled(const float* __restrict__ A,
                                                  const float* __restrict__ B,
                                                  float* __restrict__ C,
                                                  int M, int N, int K) {
    __shared__ float As[16][65];
    __shared__ float Bs[16][64];
    const int block_row = blockIdx.x * 64;
    const int block_col = blockIdx.y * 64;
    const int tid = threadIdx.x;
    const int tx = tid & 15;
    const int ty = tid >> 4;
    float c[4][4] = {};
    for (int k0 = 0; k0 < K; k0 += 16) {
#pragma unroll
        for (int i = 0; i < 4; ++i) {
            int idx = tid + i * 256;
            int kk = idx & 15;
            int m = idx >> 4;
            int row = block_row + m;
            float v = 0.f;
            if (row < M) v = A[(long)row * K + k0 + kk];
            if (RELU) v = fmaxf(v, 0.f);
            As[kk][m] = v;
        }
#pragma unroll
        for (int i = 0; i < 4; ++i) {
            int idx = tid + i * 256;
            int n = idx & 63;
            int kk = idx >> 6;
            Bs[kk][n] = B[(long)(k0 + kk) * N + block_col + n];
        }
        __syncthreads();
#pragma unroll
        for (int kk = 0; kk < 16; ++kk) {
            float a[4], b[4];
#pragma unroll
            for (int i = 0; i < 4; ++i) a[i] = As[kk][ty * 4 + i];
#pragma unroll
            for (int j = 0; j < 4; ++j) b[j] = Bs[kk][tx * 4 + j];
#pragma unroll
            for (int i = 0; i < 4; ++i)
#pragma unroll
                for (int j = 0; j < 4; ++j) c[i][j] += a[i] * b[j];
        }
        __syncthreads();
    }
#pragma unroll
    for (int i = 0; i < 4; ++i) {
        int row = block_row + ty * 4 + i;
        if (row < M) {
            float* cp = C + (long)row * N + block_col + tx * 4;
#pragma unroll
            for (int j = 0; j < 4; ++j) cp[j] = c[i][j];
        }
    }
}

__global__ __launch_bounds__(256) void scatter_conv(const float* __restrict__ h,
                                                    const int* __restrict__ src,
                                                    const int* __restrict__ dst,
                                                    const float* __restrict__ w,
                                                    float* __restrict__ z, int E) {
    const int lane = threadIdx.x & 63;
    const int wid = threadIdx.x >> 6;
    const int nwaves = (gridDim.x * blockDim.x) >> 6;
    for (int e = blockIdx.x * 4 + wid; e < E; e += nwaves) {
        int s = src[e];
        int d = dst[e];
        float ww = w[e];
        float4 v = ((const float4*)(h + (long)s * NHID))[lane];
        float* zp = z + (long)d * NHID + lane * 4;
        atomicAdd(zp + 0, ww * v.x);
        atomicAdd(zp + 1, ww * v.y);
        atomicAdd(zp + 2, ww * v.z);
        atomicAdd(zp + 3, ww * v.w);
    }
}

__global__ __launch_bounds__(256) void decode_f(const float* __restrict__ z,
                                                const int* __restrict__ ps,
                                                const int* __restrict__ pd,
                                                const float* __restrict__ Wlin,
                                                float* __restrict__ out, int P) {
    const int lane = threadIdx.x & 63;
    const int wid = threadIdx.x >> 6;
    const int nwaves = (gridDim.x * blockDim.x) >> 6;
    float wa[8], wb[8];
#pragma unroll
    for (int i = 0; i < 8; ++i) {
        wa[i] = Wlin[(lane * 4) * 2 + i];
        wb[i] = Wlin[(NHID + lane * 4) * 2 + i];
    }
    for (int p = blockIdx.x * 4 + wid; p < P; p += nwaves) {
        int a = ps[p];
        int b = pd[p];
        float4 va = ((const float4*)(z + (long)a * NHID))[lane];
        float4 vb = ((const float4*)(z + (long)b * NHID))[lane];
        float acc0 = va.x * wa[0] + va.y * wa[2] + va.z * wa[4] + va.w * wa[6]
                   + vb.x * wb[0] + vb.y * wb[2] + vb.z * wb[4] + vb.w * wb[6];
        float acc1 = va.x * wa[1] + va.y * wa[3] + va.z * wa[5] + va.w * wa[7]
                   + vb.x * wb[1] + vb.y * wb[3] + vb.z * wb[5] + vb.w * wb[7];
#pragma unroll
        for (int off = 32; off > 0; off >>= 1) {
            acc0 += __shfl_down(acc0, off);
            acc1 += __shfl_down(acc1, off);
        }
        if (lane == 0) {
            out[(long)p * 2 + 0] = acc0;
            out[(long)p * 2 + 1] = acc1;
        }
    }
}

extern "C" void kernel_launch(void* const* d_in, const int* in_sizes, int n_in,
                              void* d_out, int out_size, void* d_ws, size_t ws_size,
                              hipStream_t stream) {
    (void)n_in; (void)out_size;
    const float* x    = (const float*)d_in[0];   // [M, 512]
    const int*   ei   = (const int*)d_in[1];     // [2, E]
    const float* ew   = (const float*)d_in[2];   // [E]
    const int*   pei  = (const int*)d_in[3];     // [2, P]
    const float* W1   = (const float*)d_in[4];   // [512, 256]
    const float* W2   = (const float*)d_in[5];   // [256, 256]
    const float* Wlin = (const float*)d_in[6];   // [512, 2]
    float* out = (float*)d_out;                  // [P, 2]

    const int E = in_sizes[2];
    const int P = in_sizes[3] / 2;
    const int M = in_sizes[0] / NFEAT;

    dim3 blk(256);
    const int* src = ei;
    const int* dst = ei + E;

    // workspace layout (bf16 path)
    unsigned short* hA = (unsigned short*)d_ws;               // [M,256] bf16
    unsigned short* hB = hA + (size_t)M * NHID;               // [M,256] bf16
    int* offsets = (int*)(hB + (size_t)M * NHID);             // [M+1]
    int* cursor  = offsets + (M + 1);                          // [M]
    unsigned* pk = (unsigned*)(cursor + M);                    // [E] packed (f16 w | u16 src)
    int* blocksums = (int*)(pk + E);                           // [1024]
    float2* za = (float2*)(blocksums + 1024);                  // [M]
    float2* zb = za + M;                                       // [M]
    const size_t need = 2 * (size_t)M * NHID * 2 + ((size_t)2 * M + 1) * 4
                      + (size_t)E * 4 + 1024 * 4 + (size_t)M * 2 * 8;

    if (ws_size >= need && M <= 65535) {
        unsigned short* W1bT = (unsigned short*)d_out;        // [256,512] bf16 (256 KB)
        unsigned short* W2bT = W1bT + (size_t)NHID * NFEAT;   // [256,256] bf16 (128 KB)

        const int zt = NFEAT * NHID + NHID * NHID + M;
        transposeW2z<<<(zt + 255) / 256, blk, 0, stream>>>(W1, W2, W1bT, W2bT, cursor, M);

        // ---- CSR build (XCD-range-partitioned hist + sort) ----
        const int span = (M + 7) / 8;
        const int nb = (M + 1023) / 1024;
        hist_part<<<2048, blk, 0, stream>>>(dst, cursor, E, span, M);
        scan_local<<<nb, 1024, 0, stream>>>(cursor, offsets, blocksums, M);
        scan_sums<<<1, 1024, 0, stream>>>(blocksums, nb);
        scan_finalize<<<(M + 255) / 256, blk, 0, stream>>>(offsets, cursor, blocksums, M, E);
        sort_edges_part<<<2048, blk, 0, stream>>>(src, dst, ew, cursor, pk, E, span, M);

        // ---- Layer 1: hA = cvt(x) @ W1 ----
        dim3 g1(NHID / BN, (M + BM - 1) / BM);
        gemm1_mfma<<<g1, blk, 0, stream>>>(x, W1bT, hA, M);
        gather_conv_pk<<<(M + 3) / 4, blk, 0, stream>>>(hA, offsets, pk, hB, M);
        // ---- Layer 2 + fused Wlin projection ----
        gemm2_mfma<<<g1, blk, 0, stream>>>(hB, W2bT, hA, M);
        gather_wlin_pk<<<(M + 3) / 4, blk, 0, stream>>>(hA, offsets, pk, Wlin, za, zb, M);
        // ---- Decode ----
        decode_pairs<<<(P + 255) / 256, blk, 0, stream>>>(za, zb, pei, pei + P, (float2*)out, P);
    } else {
        // fp32 atomic fallback
        float* bufA = (float*)d_ws;
        float* bufB = bufA + (size_t)M * NHID;
        const size_t zbytes = (size_t)M * NHID * sizeof(float);
        dim3 gemm_grid((M + 63) / 64, NHID / 64);
        gemm_tiled<false><<<gemm_grid, blk, 0, stream>>>(x, W1, bufA, M, NHID, NFEAT);
        hipMemsetAsync(bufB, 0, zbytes, stream);
        scatter_conv<<<2048, blk, 0, stream>>>(bufA, src, dst, ew, bufB, E);
        gemm_tiled<true><<<gemm_grid, blk, 0, stream>>>(bufB, W2, bufA, M, NHID, NHID);
        hipMemsetAsync(bufB, 0, zbytes, stream);
        scatter_conv<<<2048, blk, 0, stream>>>(bufA, src, dst, ew, bufB, E);
        decode_f<<<(P + 3) / 4, blk, 0, stream>>>(bufB, pei, pei + P, Wlin, out, P);
    }
}